// Round 14
// baseline (513.440 us; speedup 1.0000x reference)
//
#include <hip/hip_runtime.h>
#include <stdint.h>

#define BATCH 16
#define CIN   32
#define HH    128
#define WW    128
#define BO    32
#define OCH   128   // 4*BO
#define DEPTH 64

// ws layout (compatible with fallback): [0,4096) progress; [4096,+RINGMAX)
// ring (fallback only); [4096+RINGMAX, +I2SHSZ) i2s f16 [b][t][row][o]
#define RINGMAX ((size_t)BATCH * 16 * DEPTH * BO * 8)
#define I2SHSZ  ((size_t)BATCH * WW * HH * OCH * 2)

typedef _Float16 f16x4v __attribute__((ext_vector_type(4)));
typedef _Float16 f16x8v __attribute__((ext_vector_type(8)));
typedef float    f32x4v __attribute__((ext_vector_type(4)));

// ===== K1: i2s_h[b][t][row][o] = (f16)(b2+b1 + sum_c W2[o][c]*xskew) ========
__global__ __launch_bounds__(256, 4) void i2s_gemm_h(
    const float* __restrict__ x, const float* __restrict__ W2g,
    const float* __restrict__ b2, const float* __restrict__ b1,
    _Float16* __restrict__ i2sh)
{
    const int tid = threadIdx.x;
    const int bx  = blockIdx.x;
    const int b   = bx >> 7;
    const int row = bx & 127;

    __shared__ __attribute__((aligned(16))) float xs[CIN][WW];
    __shared__ __attribute__((aligned(16))) float w2s[CIN][OCH];
    __shared__ float bs[OCH];

    for (int i = tid; i < CIN * OCH; i += 256) {
        const int c = i >> 7, o = i & 127;
        w2s[c][o] = W2g[o * CIN + c];
    }
    if (tid < OCH) bs[tid] = b2[tid] + b1[tid];
    for (int i = tid; i < CIN * WW; i += 256) {
        const int c = i >> 7, t = i & 127;
        xs[c][t] = (t >= row)
            ? x[((size_t)(b * CIN + c) * HH + row) * WW + (t - row)] : 0.f;
    }
    __syncthreads();

    const int tm = tid >> 4;
    const int tn = tid & 15;
    const int t0 = tm * 8, o0 = tn * 8;

    float bv[8];
    *(float4*)&bv[0] = *(const float4*)&bs[o0];
    *(float4*)&bv[4] = *(const float4*)&bs[o0 + 4];
    float acc[8][8];
#pragma unroll
    for (int i = 0; i < 8; ++i)
#pragma unroll
        for (int jj = 0; jj < 8; ++jj) acc[i][jj] = bv[jj];

    for (int c = 0; c < CIN; ++c) {
        float a[8], wv[8];
        *(float4*)&a[0]  = *(const float4*)&xs[c][t0];
        *(float4*)&a[4]  = *(const float4*)&xs[c][t0 + 4];
        *(float4*)&wv[0] = *(const float4*)&w2s[c][o0];
        *(float4*)&wv[4] = *(const float4*)&w2s[c][o0 + 4];
#pragma unroll
        for (int i = 0; i < 8; ++i)
#pragma unroll
            for (int jj = 0; jj < 8; ++jj)
                acc[i][jj] = fmaf(a[i], wv[jj], acc[i][jj]);
    }

#pragma unroll
    for (int i = 0; i < 8; ++i) {
        f16x8v hv;
#pragma unroll
        for (int jj = 0; jj < 8; ++jj) hv[jj] = (_Float16)acc[i][jj];
        *(f16x8v*)&i2sh[((size_t)(b * WW + (t0 + i)) * HH + row) * OCH + o0] = hv;
    }
}

// ===== K2 v14: one block/image, barrier-only, W1 IN LDS (allocator-proof).
// 6 rounds of evidence: the allocator sinks any >~16-VGPR loop-invariant
// vector set into per-step L2/scratch reloads (the ~4500cyc/step floor).
// Fix: stage W1 in LDS once; each wave re-reads its 2 B-frags per step via
// 2x ds_read_b128 (~25cyc, hidden) -> nothing left to sink, regs ~50.
// Wave w: nt = w&7 (N-tile), mg = w>>3 -> M-tiles 4mg..4mg+3 (8 MFMAs).
// Gates via gbuf (f32 LDS, 2-way banks); cells 4 rows x 1 ch per lane.
__global__ __launch_bounds__(1024) void diag_lstm_scan_v14(
    const float* __restrict__ W1g, float* __restrict__ out,
    const _Float16* __restrict__ i2sh)
{
    const int tid = threadIdx.x;
    const int l   = tid & 63;
    const int w   = tid >> 6;       // wave 0..15
    const int nt  = w & 7;          // N-tile
    const int mg  = w >> 3;         // M-group (tiles 4mg..4mg+3)
    const int kq  = l >> 4;         // 0..3
    const int col = l & 15;
    const int b   = blockIdx.x;     // 0..15

    // W1s[o][kk]: kk = 32h + 2c + which; pad 72 halfs = 144B (16B aligned)
    __shared__ _Float16 W1s[OCH][72];
    // phs[par][row+1][ch] f16; row 0 = zero boundary (never written)
    __shared__ _Float16 phs[2][HH + 1][44];
    // gates f32 [row][ch], pad 132 -> write/read both 2-way (free)
    __shared__ float gbuf[HH][132];

    for (int i = tid; i < OCH * CIN; i += 1024) {
        const int o = i >> 5, c = i & 31;
        const float2 wv = *(const float2*)&W1g[((size_t)o * CIN + c) * 2];
        W1s[o][2 * c]     = (_Float16)wv.x;   // which=0 (W1_prev)
        W1s[o][2 * c + 1] = (_Float16)wv.y;   // which=1 (W1_cur)
    }
    for (int i = tid; i < 2 * (HH + 1) * 44; i += 1024)
        (&phs[0][0][0])[i] = (_Float16)0.f;

    const int o = nt * 16 + col;

    // ---- i2s per-lane prefetch (1-deep): u[i][e] = i2s[t][64mg+16i+4kq+e][o]
    const ushort* i2su = (const ushort*)i2sh;
    const int grow0 = 64 * mg + 4 * kq;
    ushort u[4][4];
    {
        const size_t base = ((size_t)(b * WW + 0) * HH + grow0) * OCH + o;
#pragma unroll
        for (int i = 0; i < 4; ++i)
#pragma unroll
            for (int e = 0; e < 4; ++e)
                u[i][e] = i2su[base + (size_t)(16 * i + e) * OCH];
    }

    // ---- cell role: channel cj, rows cr0..cr0+3 ----
    const int cj  = tid & 31;
    const int cr0 = (tid >> 5) * 4;
    float pc[4] = {0.f, 0.f, 0.f, 0.f};

    __syncthreads();

    for (int t = 0; t < WW; ++t) {
        _Float16 (*PS)[44] = phs[t & 1];
        _Float16 (*PD)[44] = phs[(t & 1) ^ 1];

        // ---- B-frags from LDS (cheap per-step re-read; can't be "sunk") ----
        const f16x8v bw0 = *(const f16x8v*)&W1s[o][8 * kq];        // h=0: c 0..15
        const f16x8v bw1 = *(const f16x8v*)&W1s[o][32 + 8 * kq];   // h=1: c 16..31

        // ---- per M-tile: A-build, C-init, 2 MFMAs, gbuf write ----
#pragma unroll
        for (int i = 0; i < 4; ++i) {
            const int mt = 4 * mg + i;
            const int R  = 16 * mt + col;
            const f16x4v r0 = *(const f16x4v*)&PS[R][4 * kq];
            const f16x4v r1 = *(const f16x4v*)&PS[R + 1][4 * kq];
            const f16x4v r2 = *(const f16x4v*)&PS[R][16 + 4 * kq];
            const f16x4v r3 = *(const f16x4v*)&PS[R + 1][16 + 4 * kq];
            f16x8v af0, af1;
            af0[0] = r0[0]; af0[1] = r1[0]; af0[2] = r0[1]; af0[3] = r1[1];
            af0[4] = r0[2]; af0[5] = r1[2]; af0[6] = r0[3]; af0[7] = r1[3];
            af1[0] = r2[0]; af1[1] = r3[0]; af1[2] = r2[1]; af1[3] = r3[1];
            af1[4] = r2[2]; af1[5] = r3[2]; af1[6] = r2[3]; af1[7] = r3[3];

            f32x4v acc;
#pragma unroll
            for (int e = 0; e < 4; ++e) {
                ushort uv = u[i][e];
                acc[e] = (float)(*reinterpret_cast<const _Float16*>(&uv));
            }
            acc = __builtin_amdgcn_mfma_f32_16x16x32_f16(af0, bw0, acc, 0, 0, 0);
            acc = __builtin_amdgcn_mfma_f32_16x16x32_f16(af1, bw1, acc, 0, 0, 0);
#pragma unroll
            for (int e = 0; e < 4; ++e)
                gbuf[16 * mt + 4 * kq + e][o] = acc[e];
        }

        // ---- refill i2s prefetch for t+1 ----
        {
            const int tn = (t + 1 < WW) ? t + 1 : WW - 1;
            const size_t base = ((size_t)(b * WW + tn) * HH + grow0) * OCH + o;
#pragma unroll
            for (int i = 0; i < 4; ++i)
#pragma unroll
                for (int e = 0; e < 4; ++e)
                    u[i][e] = i2su[base + (size_t)(16 * i + e) * OCH];
        }

        __syncthreads();   // barrier A: gates visible

        // ---- cells: rows cr0..cr0+3, channel cj, register-local state ----
#pragma unroll
        for (int e = 0; e < 4; ++e) {
            const int r = cr0 + e;
            const float go = gbuf[r][cj];
            const float gf = gbuf[r][32 + cj];
            const float gi = gbuf[r][64 + cj];
            const float gg = gbuf[r][96 + cj];
            const float so = 1.f / (1.f + __expf(-go));
            const float sf = 1.f / (1.f + __expf(-gf));
            const float si = 1.f / (1.f + __expf(-gi));
            const float tg = 2.f / (1.f + __expf(-2.f * gg)) - 1.f;
            const float nc = sf * pc[e] + si * tg;
            const float th = 2.f / (1.f + __expf(-2.f * nc)) - 1.f;
            const float nh = so * th;
            pc[e] = nc;
            PD[r + 1][cj] = (_Float16)nh;
            out[((size_t)(b * BO + cj) * HH + r) * WW + t] = nh;
        }

        __syncthreads();   // barrier B: PD published for next step
    }
}

// ===================== fallback (R4, proven, ws-lean) =====================
__global__ __launch_bounds__(512, 2) void diag_lstm_scan_v4(
    const float* __restrict__ x, const float* __restrict__ W2g,
    const float* __restrict__ b2, const float* __restrict__ W1g,
    const float* __restrict__ b1, float* __restrict__ out,
    int* __restrict__ progress, unsigned long long* __restrict__ hand)
{
    const int tid = threadIdx.x;
    const int l   = tid & 63;
    const int w   = tid >> 6;
    const int blk = blockIdx.x;
    const int b = (blk & 7) + ((blk >> 7) << 3);
    const int k = (blk >> 3) & 15;
    const int row = k * 8 + w;

    __shared__ __attribute__((aligned(16))) float phs[2][9][BO];
    __shared__ __attribute__((aligned(16))) float xbuf[8][CIN];
    __shared__ __attribute__((aligned(16))) float gbuf2[8][OCH];

    for (int i = tid; i < 2 * 9 * BO; i += 512) ((float*)phs)[i] = 0.f;

    const int o0 = 2 * l, o1 = 2 * l + 1;
    float w2a[CIN], w2b[CIN], w1pa[CIN], w1ca[CIN], w1pb[CIN], w1cb[CIN];
#pragma unroll
    for (int c = 0; c < CIN; ++c) {
        w2a[c]  = W2g[o0 * CIN + c];
        w2b[c]  = W2g[o1 * CIN + c];
        w1pa[c] = W1g[(o0 * CIN + c) * 2 + 0];
        w1ca[c] = W1g[(o0 * CIN + c) * 2 + 1];
        w1pb[c] = W1g[(o1 * CIN + c) * 2 + 0];
        w1cb[c] = W1g[(o1 * CIN + c) * 2 + 1];
    }
    const float biasA = b2[o0] + b1[o0];
    const float biasB = b2[o1] + b1[o1];

    const int j = l & 31;
    float pc = 0.f, ob0 = 0.f, ob1 = 0.f, ob2 = 0.f;
    float* outrow = out + ((size_t)(b * BO + j) * HH + row) * WW;

    const int kprev = (k > 0) ? k - 1 : 0;
    const unsigned long long* srcbase =
        hand + (size_t)((b * 16 + kprev) * DEPTH) * BO + j;
    unsigned long long* dstbase =
        hand + (size_t)((b * 16 + k) * DEPTH) * BO + j;
    int* myprog   = progress + (b * 16 + k);
    int* consprog = myprog + 1;

    unsigned long long pre = 0ull;
    __syncthreads();

    for (int t = 0; t < WW; ++t) {
        const int par = t & 1;
        if (l < 32) {
            const int wp = t - row;
            xbuf[w][l] = (wp >= 0)
                ? x[((size_t)(b * CIN + l) * HH + row) * WW + wp] : 0.f;
        }
        if (w == 0 && k > 0) {
            if (t > 0) {
                unsigned long long q = pre;
                while (__any((unsigned)(q >> 32) != (unsigned)t)) {
                    q = __hip_atomic_load(&srcbase[(size_t)((t - 1) & (DEPTH - 1)) * BO],
                                          __ATOMIC_RELAXED, __HIP_MEMORY_SCOPE_AGENT);
                }
                if (l < 32) phs[par][0][l] = __uint_as_float((unsigned)q);
            }
            pre = __hip_atomic_load(&srcbase[(size_t)(t & (DEPTH - 1)) * BO],
                                    __ATOMIC_RELAXED, __HIP_MEMORY_SCOPE_AGENT);
        }
        asm volatile("s_waitcnt lgkmcnt(0)" ::: "memory");

        float ga = biasA, gb = biasB;
        {
            const float4* xb4 = (const float4*)(&xbuf[w][0]);
            const float4* pv4 = (const float4*)(&phs[par][w][0]);
            const float4* qv4 = (const float4*)(&phs[par][w + 1][0]);
#pragma unroll
            for (int cc = 0; cc < CIN / 4; ++cc) {
                const float4 xv = xb4[cc];
                const float4 pv = pv4[cc];
                const float4 qv = qv4[cc];
                const float* xs = (const float*)&xv;
                const float* ps = (const float*)&pv;
                const float* qs = (const float*)&qv;
#pragma unroll
                for (int ci = 0; ci < 4; ++ci) {
                    const int c = 4 * cc + ci;
                    ga = fmaf(w2a[c],  xs[ci], ga);
                    gb = fmaf(w2b[c],  xs[ci], gb);
                    ga = fmaf(w1pa[c], ps[ci], ga);
                    gb = fmaf(w1pb[c], ps[ci], gb);
                    ga = fmaf(w1ca[c], qs[ci], ga);
                    gb = fmaf(w1cb[c], qs[ci], gb);
                }
            }
        }
        *(float2*)&gbuf2[w][o0] = make_float2(ga, gb);
        asm volatile("s_waitcnt lgkmcnt(0)" ::: "memory");

        if (l < 32) {
            if (w == 7 && k < 15 && (t & 15) == 0 && t >= 48) {
                while (__hip_atomic_load(consprog, __ATOMIC_RELAXED,
                                         __HIP_MEMORY_SCOPE_AGENT) < t - 47) { }
            }
            const float go = gbuf2[w][l];
            const float gf = gbuf2[w][32 + l];
            const float gi = gbuf2[w][64 + l];
            const float gg = gbuf2[w][96 + l];
            const float so = 1.f / (1.f + __expf(-go));
            const float sf = 1.f / (1.f + __expf(-gf));
            const float si = 1.f / (1.f + __expf(-gi));
            const float tg = 2.f / (1.f + __expf(-2.f * gg)) - 1.f;
            const float nc = sf * pc + si * tg;
            const float th = 2.f / (1.f + __expf(-2.f * nc)) - 1.f;
            const float nh = so * th;
            pc = nc;
            phs[par ^ 1][w + 1][j] = nh;

            const int ph4 = t & 3;
            if (ph4 == 0) ob0 = nh;
            else if (ph4 == 1) ob1 = nh;
            else if (ph4 == 2) ob2 = nh;
            else *(float4*)(outrow + (t - 3)) = make_float4(ob0, ob1, ob2, nh);

            if (w == 7 && k < 15) {
                unsigned long long q = ((unsigned long long)(unsigned)(t + 1) << 32)
                                     | (unsigned long long)__float_as_uint(nh);
                __hip_atomic_store(&dstbase[(size_t)(t & (DEPTH - 1)) * BO], q,
                                   __ATOMIC_RELAXED, __HIP_MEMORY_SCOPE_AGENT);
            }
            if (w == 0 && l == 0) {
                __hip_atomic_store(myprog, t + 1, __ATOMIC_RELAXED,
                                   __HIP_MEMORY_SCOPE_AGENT);
            }
        }
        __syncthreads();
    }
}

extern "C" void kernel_launch(void* const* d_in, const int* in_sizes, int n_in,
                              void* d_out, int out_size, void* d_ws, size_t ws_size,
                              hipStream_t stream) {
    const float* x  = (const float*)d_in[0];
    const float* W2 = (const float*)d_in[1];
    const float* b2 = (const float*)d_in[2];
    const float* W1 = (const float*)d_in[3];
    const float* b1 = (const float*)d_in[4];
    float* out = (float*)d_out;

    int* progress = (int*)d_ws;
    unsigned long long* hand = (unsigned long long*)((char*)d_ws + 4096);
    _Float16* i2sh = (_Float16*)((char*)d_ws + 4096 + RINGMAX);

    const size_t need = 4096 + RINGMAX + I2SHSZ;

    if (ws_size >= need) {
        // v14 path: no ring state -> no memset; i2sh fully rewritten by K1
        hipLaunchKernelGGL(i2s_gemm_h, dim3(BATCH * HH), dim3(256), 0, stream,
                           x, W2, b2, b1, i2sh);
        hipLaunchKernelGGL(diag_lstm_scan_v14, dim3(BATCH), dim3(1024), 0, stream,
                           W1, out, i2sh);
    } else {
        hipMemsetAsync(d_ws, 0, 4096 + RINGMAX, stream);
        hipLaunchKernelGGL(diag_lstm_scan_v4, dim3(BATCH * 16), dim3(512), 0, stream,
                           x, W2, b2, W1, b1, out, progress, hand);
    }
}

// Round 15
// 290.228 us; speedup vs baseline: 1.7691x; 1.7691x over previous
//
#include <hip/hip_runtime.h>
#include <stdint.h>

#define BATCH 16
#define CIN   32
#define HH    128
#define WW    128
#define BO    32
#define OCH   128   // 4*BO
#define NCH   4     // chunks of 32 rows
#define RPC   32
#define DEPTH 64

#define RINGSZ ((size_t)BATCH * NCH * DEPTH * BO * 8)   // 1 MB (v15)
#define RINGV4 ((size_t)BATCH * 16 * DEPTH * BO * 8)    // 4 MB (fallback)

typedef _Float16 f16x8v __attribute__((ext_vector_type(8)));
typedef float    f32x4v __attribute__((ext_vector_type(4)));

// ===== v15: fused scan. 64 blocks x 4 waves. Wave (m,p): M-tile m (16 rows),
// N-tiles {p,p+2,p+4,p+6}; per N-tile 3 MFMAs: W2·x (K=32) + W1·[h_prev;h_cur]
// (K=64). All weights/bias read from LDS per step (allocator-proof). h kept in
// interleaved ILV layout so A-frags are raw ds_read_b128 (no repack). Cross-
// wave sync via LDS mailbox (no s_barrier -> no vmcnt(0) drain). Ring between
// chunk blocks as in v10-v12 (proven).
__global__ __launch_bounds__(256) void diag_lstm_fused_v15(
    const float* __restrict__ x,  const float* __restrict__ W2g,
    const float* __restrict__ b2, const float* __restrict__ W1g,
    const float* __restrict__ b1, float* __restrict__ out,
    int* __restrict__ progress, unsigned long long* __restrict__ hand)
{
    const int tid = threadIdx.x;
    const int l   = tid & 63;
    const int w   = tid >> 6;     // wave 0..3
    const int m   = w >> 1;       // M-tile 0..1
    const int p   = w & 1;        // N-parity
    const int kq  = l >> 4;       // 0..3
    const int col = l & 15;
    const int blk = blockIdx.x;
    const int b   = blk & 15;     // chain (b, k) strides 16 -> same XCD
    const int k   = blk >> 4;     // 0..3

    // ILV[par][r][2c+z]: z=0 -> h[r-1][c], z=1 -> h[r][c]; row 0 even = chunk
    // boundary (poll target; stays 0 for k==0). pad 68 halfs = 136B.
    __shared__ _Float16 ILV[2][33][68];
    __shared__ _Float16 W1s[OCH][72];   // [o][kk=2c+z], pad 72
    __shared__ _Float16 W2s[OCH][40];   // [o][c], pad 40
    __shared__ _Float16 xls[2][32][36]; // [par][local row][c], pad 36
    __shared__ float    bsh[OCH];
    __shared__ int      sc[4];          // per-wave step counters (mailbox)

    for (int i = tid; i < OCH * CIN; i += 256) {
        const int o = i >> 5, c = i & 31;
        const float2 wv = *(const float2*)&W1g[((size_t)o * CIN + c) * 2];
        W1s[o][2 * c]     = (_Float16)wv.x;
        W1s[o][2 * c + 1] = (_Float16)wv.y;
        W2s[o][c]         = (_Float16)W2g[(size_t)o * CIN + c];
    }
    if (tid < OCH) bsh[tid] = b2[tid] + b1[tid];
    for (int i = tid; i < 2 * 33 * 68; i += 256) (&ILV[0][0][0])[i] = (_Float16)0.f;
    if (tid < 4) sc[tid] = 0;

    // x staging role: thread stages row sr (local), c quad sc4
    const int sr  = tid >> 3;            // 0..31
    const int sc4 = (tid & 7) * 4;       // c quad
    const int srow = k * RPC + sr;       // global row staged
    // stage t=0
    {
        const int wp = 0 - srow;
#pragma unroll
        for (int e = 0; e < 4; ++e)
            xls[0][sr][sc4 + e] = (wp >= 0)
                ? (_Float16)x[((size_t)(b * CIN + sc4 + e) * HH + srow) * WW + wp]
                : (_Float16)0.f;
    }

    // cell geometry: 4 cells/lane at rows rl0..rl0+3, channel j
    const int j     = 16 * p + col;
    const int rl0   = 16 * m + 4 * kq;
    const int grow0 = k * RPC + rl0;
    float pc[4] = {0.f, 0.f, 0.f, 0.f};

    const unsigned long long* srcring =
        hand + ((size_t)(b * NCH + (k > 0 ? k - 1 : 0)) * DEPTH) * BO + l;
    unsigned long long* dstring =
        hand + ((size_t)(b * NCH + k) * DEPTH) * BO + j;
    int* myprog   = progress + (b * NCH + k);
    int* consprog = myprog + 1;
    unsigned long long pre = 0ull;

    __syncthreads();

    for (int t = 0; t < WW; ++t) {
        const int par = t & 1;
        _Float16 (*PS)[68] = ILV[par];
        _Float16 (*PD)[68] = ILV[par ^ 1];

        // ---- ring poll: both m=0 waves redundantly (idempotent writes) ----
        if (w <= 1 && k > 0 && t > 0) {
            unsigned long long qv = pre;
            while (__any(l < 32 && (unsigned)(qv >> 32) != (unsigned)t)) {
                if (l < 32)
                    qv = __hip_atomic_load(&srcring[(size_t)((t - 1) & 63) * BO],
                                           __ATOMIC_RELAXED, __HIP_MEMORY_SCOPE_AGENT);
            }
            if (l < 32) {
                PS[0][2 * l] = (_Float16)__uint_as_float((unsigned)qv);
                pre = __hip_atomic_load(&srcring[(size_t)(t & 63) * BO],
                                        __ATOMIC_RELAXED, __HIP_MEMORY_SCOPE_AGENT);
            }
        }
        asm volatile("s_waitcnt lgkmcnt(0)" ::: "memory");

        // ---- A fragments: 2 raw b128 reads (ILV) + x frag from xls ----
        const f16x8v af0 = *(const f16x8v*)&PS[16 * m + col][8 * kq];
        const f16x8v af1 = *(const f16x8v*)&PS[16 * m + col][32 + 8 * kq];
        const f16x8v af2 = *(const f16x8v*)&xls[par][16 * m + col][8 * kq];

        // ---- stage x for t+1 into xls[par^1] (consumed after flag sync) ----
        {
            const int tn = (t + 1 < WW) ? t + 1 : WW - 1;
            const int wp = tn - srow;
#pragma unroll
            for (int e = 0; e < 4; ++e)
                xls[par ^ 1][sr][sc4 + e] = (wp >= 0)
                    ? (_Float16)x[((size_t)(b * CIN + sc4 + e) * HH + srow) * WW + wp]
                    : (_Float16)0.f;
        }

        // ---- 4 channel-groups x 3 MFMAs (weights from LDS each step) ----
        f32x4v acc[4];
#pragma unroll
        for (int s = 0; s < 4; ++s) {
            const int o = (p + 2 * s) * 16 + col;
            const float bv = bsh[o];
            acc[s][0] = bv; acc[s][1] = bv; acc[s][2] = bv; acc[s][3] = bv;
            const f16x8v bw2 = *(const f16x8v*)&W2s[o][8 * kq];
            const f16x8v bw0 = *(const f16x8v*)&W1s[o][8 * kq];
            const f16x8v bw1 = *(const f16x8v*)&W1s[o][32 + 8 * kq];
            acc[s] = __builtin_amdgcn_mfma_f32_16x16x32_f16(af2, bw2, acc[s], 0, 0, 0);
            acc[s] = __builtin_amdgcn_mfma_f32_16x16x32_f16(af0, bw0, acc[s], 0, 0, 0);
            acc[s] = __builtin_amdgcn_mfma_f32_16x16x32_f16(af1, bw1, acc[s], 0, 0, 0);
        }

        // ---- back-pressure: keep ring lead < DEPTH ----
        if (m == 1 && k < NCH - 1 && l == 0 && (t & 15) == 0 && t >= 48) {
            while (__hip_atomic_load(consprog, __ATOMIC_RELAXED,
                                     __HIP_MEMORY_SCOPE_AGENT) < t - 39) { }
        }

        // ---- cells: 4/lane, register-local (D-frag alignment) ----
#pragma unroll
        for (int e = 0; e < 4; ++e) {
            const float go = acc[0][e], gf = acc[1][e], gi = acc[2][e], gg = acc[3][e];
            const float so = 1.f / (1.f + __expf(-go));
            const float sf = 1.f / (1.f + __expf(-gf));
            const float si = 1.f / (1.f + __expf(-gi));
            const float tg = 2.f / (1.f + __expf(-2.f * gg)) - 1.f;
            const float nc = sf * pc[e] + si * tg;
            const float th = 2.f / (1.f + __expf(-2.f * nc)) - 1.f;
            const float nh = so * th;
            pc[e] = nc;
            const int rl = rl0 + e;
            PD[rl][2 * j + 1] = (_Float16)nh;       // cur-slot of A-row rl
            PD[rl + 1][2 * j] = (_Float16)nh;       // prev-slot of A-row rl+1
            out[((size_t)(b * BO + j) * HH + (grow0 + e)) * WW + t] = nh;
            if (m == 1 && kq == 3 && e == 3 && k < NCH - 1) {   // local row 31
                unsigned long long qq =
                    ((unsigned long long)(unsigned)(t + 1) << 32)
                  | (unsigned long long)__float_as_uint(nh);
                __hip_atomic_store(&dstring[(size_t)(t & 63) * BO], qq,
                                   __ATOMIC_RELAXED, __HIP_MEMORY_SCOPE_AGENT);
            }
        }
        if (w == 0 && l == 0) {
            __hip_atomic_store(myprog, t + 1, __ATOMIC_RELAXED,
                               __HIP_MEMORY_SCOPE_AGENT);
        }

        // ---- LDS mailbox sync (ds-only; avoids s_barrier's vmcnt(0) drain) ----
        asm volatile("s_waitcnt lgkmcnt(0)" ::: "memory");   // PD/xls writes done
        if (l == 0)
            __hip_atomic_store(&sc[w], t + 1, __ATOMIC_RELAXED,
                               __HIP_MEMORY_SCOPE_WORKGROUP);
        for (;;) {
            const int v0 = __hip_atomic_load(&sc[0], __ATOMIC_RELAXED,
                                             __HIP_MEMORY_SCOPE_WORKGROUP);
            const int v1 = __hip_atomic_load(&sc[1], __ATOMIC_RELAXED,
                                             __HIP_MEMORY_SCOPE_WORKGROUP);
            const int v2 = __hip_atomic_load(&sc[2], __ATOMIC_RELAXED,
                                             __HIP_MEMORY_SCOPE_WORKGROUP);
            const int v3 = __hip_atomic_load(&sc[3], __ATOMIC_RELAXED,
                                             __HIP_MEMORY_SCOPE_WORKGROUP);
            if (v0 >= t + 1 && v1 >= t + 1 && v2 >= t + 1 && v3 >= t + 1) break;
        }
    }
}

// ===================== fallback (R4, proven, ws-lean) =====================
__global__ __launch_bounds__(512, 2) void diag_lstm_scan_v4(
    const float* __restrict__ x, const float* __restrict__ W2g,
    const float* __restrict__ b2, const float* __restrict__ W1g,
    const float* __restrict__ b1, float* __restrict__ out,
    int* __restrict__ progress, unsigned long long* __restrict__ hand)
{
    const int tid = threadIdx.x;
    const int l   = tid & 63;
    const int w   = tid >> 6;
    const int blk = blockIdx.x;
    const int b = (blk & 7) + ((blk >> 7) << 3);
    const int k = (blk >> 3) & 15;
    const int row = k * 8 + w;

    __shared__ __attribute__((aligned(16))) float phs[2][9][BO];
    __shared__ __attribute__((aligned(16))) float xbuf[8][CIN];
    __shared__ __attribute__((aligned(16))) float gbuf2[8][OCH];

    for (int i = tid; i < 2 * 9 * BO; i += 512) ((float*)phs)[i] = 0.f;

    const int o0 = 2 * l, o1 = 2 * l + 1;
    float w2a[CIN], w2b[CIN], w1pa[CIN], w1ca[CIN], w1pb[CIN], w1cb[CIN];
#pragma unroll
    for (int c = 0; c < CIN; ++c) {
        w2a[c]  = W2g[o0 * CIN + c];
        w2b[c]  = W2g[o1 * CIN + c];
        w1pa[c] = W1g[(o0 * CIN + c) * 2 + 0];
        w1ca[c] = W1g[(o0 * CIN + c) * 2 + 1];
        w1pb[c] = W1g[(o1 * CIN + c) * 2 + 0];
        w1cb[c] = W1g[(o1 * CIN + c) * 2 + 1];
    }
    const float biasA = b2[o0] + b1[o0];
    const float biasB = b2[o1] + b1[o1];

    const int j = l & 31;
    float pc = 0.f, ob0 = 0.f, ob1 = 0.f, ob2 = 0.f;
    float* outrow = out + ((size_t)(b * BO + j) * HH + row) * WW;

    const int kprev = (k > 0) ? k - 1 : 0;
    const unsigned long long* srcbase =
        hand + (size_t)((b * 16 + kprev) * DEPTH) * BO + j;
    unsigned long long* dstbase =
        hand + (size_t)((b * 16 + k) * DEPTH) * BO + j;
    int* myprog   = progress + (b * 16 + k);
    int* consprog = myprog + 1;

    unsigned long long pre = 0ull;
    __syncthreads();

    for (int t = 0; t < WW; ++t) {
        const int par = t & 1;
        if (l < 32) {
            const int wp = t - row;
            xbuf[w][l] = (wp >= 0)
                ? x[((size_t)(b * CIN + l) * HH + row) * WW + wp] : 0.f;
        }
        if (w == 0 && k > 0) {
            if (t > 0) {
                unsigned long long q = pre;
                while (__any((unsigned)(q >> 32) != (unsigned)t)) {
                    q = __hip_atomic_load(&srcbase[(size_t)((t - 1) & (DEPTH - 1)) * BO],
                                          __ATOMIC_RELAXED, __HIP_MEMORY_SCOPE_AGENT);
                }
                if (l < 32) phs[par][0][l] = __uint_as_float((unsigned)q);
            }
            pre = __hip_atomic_load(&srcbase[(size_t)(t & (DEPTH - 1)) * BO],
                                    __ATOMIC_RELAXED, __HIP_MEMORY_SCOPE_AGENT);
        }
        asm volatile("s_waitcnt lgkmcnt(0)" ::: "memory");

        float ga = biasA, gb = biasB;
        {
            const float4* xb4 = (const float4*)(&xbuf[w][0]);
            const float4* pv4 = (const float4*)(&phs[par][w][0]);
            const float4* qv4 = (const float4*)(&phs[par][w + 1][0]);
#pragma unroll
            for (int cc = 0; cc < CIN / 4; ++cc) {
                const float4 xv = xb4[cc];
                const float4 pv = pv4[cc];
                const float4 qv = qv4[cc];
                const float* xs = (const float*)&xv;
                const float* ps = (const float*)&pv;
                const float* qs = (const float*)&qv;
#pragma unroll
                for (int ci = 0; ci < 4; ++ci) {
                    const int c = 4 * cc + ci;
                    ga = fmaf(w2a[c],  xs[ci], ga);
                    gb = fmaf(w2b[c],  xs[ci], gb);
                    ga = fmaf(w1pa[c], ps[ci], ga);
                    gb = fmaf(w1pb[c], ps[ci], gb);
                    ga = fmaf(w1ca[c], qs[ci], ga);
                    gb = fmaf(w1cb[c], qs[ci], gb);
                }
            }
        }
        *(float2*)&gbuf2[w][o0] = make_float2(ga, gb);
        asm volatile("s_waitcnt lgkmcnt(0)" ::: "memory");

        if (l < 32) {
            if (w == 7 && k < 15 && (t & 15) == 0 && t >= 48) {
                while (__hip_atomic_load(consprog, __ATOMIC_RELAXED,
                                         __HIP_MEMORY_SCOPE_AGENT) < t - 47) { }
            }
            const float go = gbuf2[w][l];
            const float gf = gbuf2[w][32 + l];
            const float gi = gbuf2[w][64 + l];
            const float gg = gbuf2[w][96 + l];
            const float so = 1.f / (1.f + __expf(-go));
            const float sf = 1.f / (1.f + __expf(-gf));
            const float si = 1.f / (1.f + __expf(-gi));
            const float tg = 2.f / (1.f + __expf(-2.f * gg)) - 1.f;
            const float nc = sf * pc + si * tg;
            const float th = 2.f / (1.f + __expf(-2.f * nc)) - 1.f;
            const float nh = so * th;
            pc = nc;
            phs[par ^ 1][w + 1][j] = nh;

            const int ph4 = t & 3;
            if (ph4 == 0) ob0 = nh;
            else if (ph4 == 1) ob1 = nh;
            else if (ph4 == 2) ob2 = nh;
            else *(float4*)(outrow + (t - 3)) = make_float4(ob0, ob1, ob2, nh);

            if (w == 7 && k < 15) {
                unsigned long long q = ((unsigned long long)(unsigned)(t + 1) << 32)
                                     | (unsigned long long)__float_as_uint(nh);
                __hip_atomic_store(&dstbase[(size_t)(t & (DEPTH - 1)) * BO], q,
                                   __ATOMIC_RELAXED, __HIP_MEMORY_SCOPE_AGENT);
            }
            if (w == 0 && l == 0) {
                __hip_atomic_store(myprog, t + 1, __ATOMIC_RELAXED,
                                   __HIP_MEMORY_SCOPE_AGENT);
            }
        }
        __syncthreads();
    }
}

extern "C" void kernel_launch(void* const* d_in, const int* in_sizes, int n_in,
                              void* d_out, int out_size, void* d_ws, size_t ws_size,
                              hipStream_t stream) {
    const float* x  = (const float*)d_in[0];
    const float* W2 = (const float*)d_in[1];
    const float* b2 = (const float*)d_in[2];
    const float* W1 = (const float*)d_in[3];
    const float* b1 = (const float*)d_in[4];
    float* out = (float*)d_out;

    int* progress = (int*)d_ws;
    unsigned long long* hand = (unsigned long long*)((char*)d_ws + 4096);

    if (ws_size >= 4096 + RINGSZ) {
        // clear progress + ring tags (stale tags alias across graph replays)
        hipMemsetAsync(d_ws, 0, 4096 + RINGSZ, stream);
        hipLaunchKernelGGL(diag_lstm_fused_v15, dim3(BATCH * NCH), dim3(256), 0,
                           stream, x, W2, b2, W1, b1, out, progress, hand);
    } else {
        hipMemsetAsync(d_ws, 0, 4096 + RINGV4, stream);
        hipLaunchKernelGGL(diag_lstm_scan_v4, dim3(BATCH * 16), dim3(512), 0,
                           stream, x, W2, b2, W1, b1, out, progress, hand);
    }
}

// Round 16
// 266.788 us; speedup vs baseline: 1.9245x; 1.0879x over previous
//
#include <hip/hip_runtime.h>
#include <stdint.h>

#define BATCH 16
#define CIN   32
#define HH    128
#define WW    128
#define BO    32
#define OCH   128   // 4*BO
#define NCH   16    // h-chunks (8 rows each)
#define DEPTH 64    // handoff ring depth

#define PHP   40    // padded phs row
#define GBP   132   // padded gbuf row

// ws: [0,4096) progress ints
//     [4096, +RINGSZ) tagged handoff ring
//     [4096+RINGSZ, +I2SHSZ) i2s buffer (f16, layout [b][t][row][o])
#define RINGSZ ((size_t)BATCH * NCH * DEPTH * BO * 8)
#define I2SHSZ ((size_t)BATCH * WW * HH * OCH * 2)

typedef _Float16 f16x8 __attribute__((ext_vector_type(8)));
typedef float    f32x4 __attribute__((ext_vector_type(4)));

// ===== K1: i2s_h[b][t][row][o] = (f16)(b2+b1 + sum_c W2[o][c]*xskew) ========
__global__ __launch_bounds__(256, 4) void i2s_gemm_h(
    const float* __restrict__ x, const float* __restrict__ W2g,
    const float* __restrict__ b2, const float* __restrict__ b1,
    _Float16* __restrict__ i2sh)
{
    const int tid = threadIdx.x;
    const int bx  = blockIdx.x;
    const int b   = bx >> 7;
    const int row = bx & 127;

    __shared__ __attribute__((aligned(16))) float xs[CIN][WW];
    __shared__ __attribute__((aligned(16))) float w2s[CIN][OCH];
    __shared__ float bs[OCH];

    for (int i = tid; i < CIN * OCH; i += 256) {
        const int c = i >> 7, o = i & 127;
        w2s[c][o] = W2g[o * CIN + c];
    }
    if (tid < OCH) bs[tid] = b2[tid] + b1[tid];
    for (int i = tid; i < CIN * WW; i += 256) {
        const int c = i >> 7, t = i & 127;
        xs[c][t] = (t >= row)
            ? x[((size_t)(b * CIN + c) * HH + row) * WW + (t - row)] : 0.f;
    }
    __syncthreads();

    const int tm = tid >> 4;
    const int tn = tid & 15;
    const int t0 = tm * 8, o0 = tn * 8;

    float bv[8];
    *(float4*)&bv[0] = *(const float4*)&bs[o0];
    *(float4*)&bv[4] = *(const float4*)&bs[o0 + 4];
    float acc[8][8];
#pragma unroll
    for (int i = 0; i < 8; ++i)
#pragma unroll
        for (int jj = 0; jj < 8; ++jj) acc[i][jj] = bv[jj];

    for (int c = 0; c < CIN; ++c) {
        float a[8], wv[8];
        *(float4*)&a[0]  = *(const float4*)&xs[c][t0];
        *(float4*)&a[4]  = *(const float4*)&xs[c][t0 + 4];
        *(float4*)&wv[0] = *(const float4*)&w2s[c][o0];
        *(float4*)&wv[4] = *(const float4*)&w2s[c][o0 + 4];
#pragma unroll
        for (int i = 0; i < 8; ++i)
#pragma unroll
            for (int jj = 0; jj < 8; ++jj)
                acc[i][jj] = fmaf(a[i], wv[jj], acc[i][jj]);
    }

#pragma unroll
    for (int i = 0; i < 8; ++i) {
        f16x8 hv;
#pragma unroll
        for (int jj = 0; jj < 8; ++jj) hv[jj] = (_Float16)acc[i][jj];
        *(f16x8*)&i2sh[((size_t)(b * WW + (t0 + i)) * HH + row) * OCH + o0] = hv;
    }
}

// ===== K2 v16: v10 verbatim, with the two __syncthreads replaced by an
// LDS generation-counter mailbox. s_barrier forces a vmcnt(0) drain of the
// in-flight ibuf prefetch loads (+ out stores) every step (~1000+cyc of the
// measured 2400cyc step). The ds-only mailbox lets those stay outstanding.
__global__ __launch_bounds__(512) void diag_lstm_scan_v16(
    const float* __restrict__ W1g, float* __restrict__ out,
    int* __restrict__ progress, unsigned long long* __restrict__ hand,
    const _Float16* __restrict__ i2sh)
{
    const int tid = threadIdx.x;
    const int l   = tid & 63;
    const int wv  = tid >> 6;          // wave 0..7
    const int blk = blockIdx.x;
    const int b = (blk & 7) + ((blk >> 7) << 3);   // XCD-affinity remap
    const int k = (blk >> 3) & (NCH - 1);

    __shared__ __attribute__((aligned(16))) float    phs[2][9][PHP];
    __shared__ __attribute__((aligned(16))) float    gbuf[8][GBP];
    __shared__ __attribute__((aligned(16))) _Float16 ibuf[2][8][OCH];
    __shared__ int gen[8];

    for (int i = tid; i < 2 * 9 * PHP; i += 512) ((float*)phs)[i] = 0.f;
    if (tid < 8) gen[tid] = 0;

    // ---- B-frags: W[o][kk] = W1g[o*64 + kk], loaded once (8 VGPRs/lane ok) ----
    const int n  = l & 15;
    const int kq = l >> 4;
    const int o  = wv * 16 + n;
    f16x8 bw0, bw1;
    {
        const float4 a0 = *(const float4*)&W1g[(size_t)o * 64 + 8 * kq];
        const float4 a1 = *(const float4*)&W1g[(size_t)o * 64 + 8 * kq + 4];
        const float4 c0 = *(const float4*)&W1g[(size_t)o * 64 + 32 + 8 * kq];
        const float4 c1 = *(const float4*)&W1g[(size_t)o * 64 + 32 + 8 * kq + 4];
        bw0[0] = (_Float16)a0.x; bw0[1] = (_Float16)a0.y;
        bw0[2] = (_Float16)a0.z; bw0[3] = (_Float16)a0.w;
        bw0[4] = (_Float16)a1.x; bw0[5] = (_Float16)a1.y;
        bw0[6] = (_Float16)a1.z; bw0[7] = (_Float16)a1.w;
        bw1[0] = (_Float16)c0.x; bw1[1] = (_Float16)c0.y;
        bw1[2] = (_Float16)c0.z; bw1[3] = (_Float16)c0.w;
        bw1[4] = (_Float16)c1.x; bw1[5] = (_Float16)c1.y;
        bw1[6] = (_Float16)c1.z; bw1[7] = (_Float16)c1.w;
    }

    // ---- cell role (waves 0..3): row r = 2wv + (l>>5), channel j = l&31 ----
    const int r = (2 * wv + (l >> 5)) & 7;
    const int j = l & 31;
    float pc = 0.f, ob0 = 0.f, ob1 = 0.f, ob2 = 0.f;
    float* outrow = out + ((size_t)(b * BO + j) * HH + (k * 8 + r)) * WW;

    // ---- ring handoff ----
    const int kprev = (k > 0) ? k - 1 : 0;
    const unsigned long long* srcbase =
        hand + (size_t)((b * NCH + kprev) * DEPTH) * BO + j;
    unsigned long long* dstbase =
        hand + (size_t)((b * NCH + k) * DEPTH) * BO + j;
    int* myprog   = progress + (b * NCH + k);
    int* consprog = myprog + 1;
    unsigned long long pre = 0ull;

    // ---- i2s prefetch: [b][t][row][o] f16; block slice = 8 rows = 2KB/t ----
    const size_t islab = (size_t)HH * OCH;
    const _Float16* ibase0 = i2sh + ((size_t)(b * WW) * HH + k * 8) * OCH;
    const int ii = tid & 255;
    uint2 pr0 = make_uint2(0, 0), pr1 = make_uint2(0, 0);

    ((unsigned int*)&ibuf[0][0][0])[tid] = ((const unsigned int*)ibase0)[tid]; // t=0
    if (wv >= 4) {
        pr0 = ((const uint2*)(ibase0 + 1 * islab))[ii];   // t=1
        pr1 = ((const uint2*)(ibase0 + 2 * islab))[ii];   // t=2
    }
    __syncthreads();

    for (int t = 0; t < WW; ++t) {
        const int par = t & 1;

        // ---- boundary poll (all waves, idempotent writes) ----
        if (k > 0 && t > 0) {
            unsigned long long q = pre;
            while (__any((unsigned)(q >> 32) != (unsigned)t)) {
                q = __hip_atomic_load(&srcbase[(size_t)((t - 1) & (DEPTH - 1)) * BO],
                                      __ATOMIC_RELAXED, __HIP_MEMORY_SCOPE_AGENT);
            }
            if (l < 32) phs[par][0][l] = __uint_as_float((unsigned)q);
            pre = __hip_atomic_load(&srcbase[(size_t)(t & (DEPTH - 1)) * BO],
                                    __ATOMIC_RELAXED, __HIP_MEMORY_SCOPE_AGENT);
            asm volatile("s_waitcnt lgkmcnt(0)" ::: "memory");
        }

        // ---- A-frags from phs (m = n = l&15; rows >= 8 are zero padding) ----
        f16x8 af0 = {}; f16x8 af1 = {};
        if (n < 8) {
            const float4 P0 = *(const float4*)&phs[par][n    ][4 * kq];
            const float4 Q0 = *(const float4*)&phs[par][n + 1][4 * kq];
            const float4 P1 = *(const float4*)&phs[par][n    ][16 + 4 * kq];
            const float4 Q1 = *(const float4*)&phs[par][n + 1][16 + 4 * kq];
            af0[0] = (_Float16)P0.x; af0[1] = (_Float16)Q0.x;
            af0[2] = (_Float16)P0.y; af0[3] = (_Float16)Q0.y;
            af0[4] = (_Float16)P0.z; af0[5] = (_Float16)Q0.z;
            af0[6] = (_Float16)P0.w; af0[7] = (_Float16)Q0.w;
            af1[0] = (_Float16)P1.x; af1[1] = (_Float16)Q1.x;
            af1[2] = (_Float16)P1.y; af1[3] = (_Float16)Q1.y;
            af1[4] = (_Float16)P1.z; af1[5] = (_Float16)Q1.z;
            af1[6] = (_Float16)P1.w; af1[7] = (_Float16)Q1.w;
        }

        f32x4 acc = {0.f, 0.f, 0.f, 0.f};
        acc = __builtin_amdgcn_mfma_f32_16x16x32_f16(af0, bw0, acc, 0, 0, 0);
        acc = __builtin_amdgcn_mfma_f32_16x16x32_f16(af1, bw1, acc, 0, 0, 0);

        // ---- gate write: lane l<32 holds rows 4*kq+e, col n ----
        if (l < 32) {
#pragma unroll
            for (int e = 0; e < 4; ++e)
                gbuf[4 * kq + e][wv * 16 + n] = acc[e];
        }

        // ---- waves 4..7: stage i2s for t+1, issue load for t+3 ----
        if (wv >= 4) {
            ((uint2*)&ibuf[(t + 1) & 1][0][0])[ii] = pr0;   // waits only pr0's vmcnt
            pr0 = pr1;
            const int t3 = (t + 3 < WW) ? t + 3 : WW - 1;
            pr1 = ((const uint2*)(ibase0 + (size_t)t3 * islab))[ii];
        }

        // ==== mailbox sync A (ds-only; prefetch loads stay in flight) ====
        {
            const int tgt = 2 * t + 1;
            asm volatile("s_waitcnt lgkmcnt(0)" ::: "memory");
            if (l == 0) *(volatile int*)&gen[wv] = tgt;
            for (;;) {
                int m0 = *(volatile int*)&gen[0];
                int m1 = *(volatile int*)&gen[1];
                int m2 = *(volatile int*)&gen[2];
                int m3 = *(volatile int*)&gen[3];
                int m4 = *(volatile int*)&gen[4];
                int m5 = *(volatile int*)&gen[5];
                int m6 = *(volatile int*)&gen[6];
                int m7 = *(volatile int*)&gen[7];
                int mn = min(min(min(m0, m1), min(m2, m3)),
                             min(min(m4, m5), min(m6, m7)));
                if (mn >= tgt) break;
            }
        }

        // ---- cell update (waves 0..3) ----
        if (wv < 4) {
            if (wv == 3 && l >= 32 && k < NCH - 1 && (t & 15) == 0 && t >= 48) {
                while (__hip_atomic_load(consprog, __ATOMIC_RELAXED,
                                         __HIP_MEMORY_SCOPE_AGENT) < t - 47) { }
            }
            const float go = gbuf[r][j]      + (float)ibuf[par][r][j];
            const float gf = gbuf[r][32 + j] + (float)ibuf[par][r][32 + j];
            const float gi = gbuf[r][64 + j] + (float)ibuf[par][r][64 + j];
            const float gg = gbuf[r][96 + j] + (float)ibuf[par][r][96 + j];
            const float so = 1.f / (1.f + __expf(-go));
            const float sf = 1.f / (1.f + __expf(-gf));
            const float si = 1.f / (1.f + __expf(-gi));
            const float tg = 2.f / (1.f + __expf(-2.f * gg)) - 1.f;
            const float nc = sf * pc + si * tg;
            const float th = 2.f / (1.f + __expf(-2.f * nc)) - 1.f;
            const float nh = so * th;
            pc = nc;
            phs[par ^ 1][r + 1][j] = nh;

            const int ph4 = t & 3;
            if (ph4 == 0) ob0 = nh;
            else if (ph4 == 1) ob1 = nh;
            else if (ph4 == 2) ob2 = nh;
            else *(float4*)(outrow + (t - 3)) = make_float4(ob0, ob1, ob2, nh);

            if (wv == 3 && l >= 32 && k < NCH - 1) {   // r==7: handoff
                unsigned long long qq = ((unsigned long long)(unsigned)(t + 1) << 32)
                                      | (unsigned long long)__float_as_uint(nh);
                __hip_atomic_store(&dstbase[(size_t)(t & (DEPTH - 1)) * BO], qq,
                                   __ATOMIC_RELAXED, __HIP_MEMORY_SCOPE_AGENT);
            }
            if (tid == 0) {
                __hip_atomic_store(myprog, t + 1, __ATOMIC_RELAXED,
                                   __HIP_MEMORY_SCOPE_AGENT);
            }
        }

        // ==== mailbox sync B (phs[par^1] published; out stores not drained) ====
        {
            const int tgt = 2 * t + 2;
            asm volatile("s_waitcnt lgkmcnt(0)" ::: "memory");
            if (l == 0) *(volatile int*)&gen[wv] = tgt;
            for (;;) {
                int m0 = *(volatile int*)&gen[0];
                int m1 = *(volatile int*)&gen[1];
                int m2 = *(volatile int*)&gen[2];
                int m3 = *(volatile int*)&gen[3];
                int m4 = *(volatile int*)&gen[4];
                int m5 = *(volatile int*)&gen[5];
                int m6 = *(volatile int*)&gen[6];
                int m7 = *(volatile int*)&gen[7];
                int mn = min(min(min(m0, m1), min(m2, m3)),
                             min(min(m4, m5), min(m6, m7)));
                if (mn >= tgt) break;
            }
        }
    }
}

// ===================== fallback (R4, proven, ws-lean) =====================
__global__ __launch_bounds__(512, 2) void diag_lstm_scan_v4(
    const float* __restrict__ x, const float* __restrict__ W2g,
    const float* __restrict__ b2, const float* __restrict__ W1g,
    const float* __restrict__ b1, float* __restrict__ out,
    int* __restrict__ progress, unsigned long long* __restrict__ hand)
{
    const int tid = threadIdx.x;
    const int l   = tid & 63;
    const int w   = tid >> 6;
    const int blk = blockIdx.x;
    const int b = (blk & 7) + ((blk >> 7) << 3);
    const int k = (blk >> 3) & 15;
    const int row = k * 8 + w;

    __shared__ __attribute__((aligned(16))) float phs[2][9][BO];
    __shared__ __attribute__((aligned(16))) float xbuf[8][CIN];
    __shared__ __attribute__((aligned(16))) float gbuf2[8][OCH];

    for (int i = tid; i < 2 * 9 * BO; i += 512) ((float*)phs)[i] = 0.f;

    const int o0 = 2 * l, o1 = 2 * l + 1;
    float w2a[CIN], w2b[CIN], w1pa[CIN], w1ca[CIN], w1pb[CIN], w1cb[CIN];
#pragma unroll
    for (int c = 0; c < CIN; ++c) {
        w2a[c]  = W2g[o0 * CIN + c];
        w2b[c]  = W2g[o1 * CIN + c];
        w1pa[c] = W1g[(o0 * CIN + c) * 2 + 0];
        w1ca[c] = W1g[(o0 * CIN + c) * 2 + 1];
        w1pb[c] = W1g[(o1 * CIN + c) * 2 + 0];
        w1cb[c] = W1g[(o1 * CIN + c) * 2 + 1];
    }
    const float biasA = b2[o0] + b1[o0];
    const float biasB = b2[o1] + b1[o1];

    const int j = l & 31;
    float pc = 0.f, ob0 = 0.f, ob1 = 0.f, ob2 = 0.f;
    float* outrow = out + ((size_t)(b * BO + j) * HH + row) * WW;

    const int kprev = (k > 0) ? k - 1 : 0;
    const unsigned long long* srcbase =
        hand + (size_t)((b * 16 + kprev) * DEPTH) * BO + j;
    unsigned long long* dstbase =
        hand + (size_t)((b * 16 + k) * DEPTH) * BO + j;
    int* myprog   = progress + (b * 16 + k);
    int* consprog = myprog + 1;

    unsigned long long pre = 0ull;
    __syncthreads();

    for (int t = 0; t < WW; ++t) {
        const int par = t & 1;
        if (l < 32) {
            const int wp = t - row;
            xbuf[w][l] = (wp >= 0)
                ? x[((size_t)(b * CIN + l) * HH + row) * WW + wp] : 0.f;
        }
        if (w == 0 && k > 0) {
            if (t > 0) {
                unsigned long long q = pre;
                while (__any((unsigned)(q >> 32) != (unsigned)t)) {
                    q = __hip_atomic_load(&srcbase[(size_t)((t - 1) & (DEPTH - 1)) * BO],
                                          __ATOMIC_RELAXED, __HIP_MEMORY_SCOPE_AGENT);
                }
                if (l < 32) phs[par][0][l] = __uint_as_float((unsigned)q);
            }
            pre = __hip_atomic_load(&srcbase[(size_t)(t & (DEPTH - 1)) * BO],
                                    __ATOMIC_RELAXED, __HIP_MEMORY_SCOPE_AGENT);
        }
        asm volatile("s_waitcnt lgkmcnt(0)" ::: "memory");

        float ga = biasA, gb = biasB;
        {
            const float4* xb4 = (const float4*)(&xbuf[w][0]);
            const float4* pv4 = (const float4*)(&phs[par][w][0]);
            const float4* qv4 = (const float4*)(&phs[par][w + 1][0]);
#pragma unroll
            for (int cc = 0; cc < CIN / 4; ++cc) {
                const float4 xv = xb4[cc];
                const float4 pv = pv4[cc];
                const float4 qv = qv4[cc];
                const float* xs = (const float*)&xv;
                const float* ps = (const float*)&pv;
                const float* qs = (const float*)&qv;
#pragma unroll
                for (int ci = 0; ci < 4; ++ci) {
                    const int c = 4 * cc + ci;
                    ga = fmaf(w2a[c],  xs[ci], ga);
                    gb = fmaf(w2b[c],  xs[ci], gb);
                    ga = fmaf(w1pa[c], ps[ci], ga);
                    gb = fmaf(w1pb[c], ps[ci], gb);
                    ga = fmaf(w1ca[c], qs[ci], ga);
                    gb = fmaf(w1cb[c], qs[ci], gb);
                }
            }
        }
        *(float2*)&gbuf2[w][o0] = make_float2(ga, gb);
        asm volatile("s_waitcnt lgkmcnt(0)" ::: "memory");

        if (l < 32) {
            if (w == 7 && k < 15 && (t & 15) == 0 && t >= 48) {
                while (__hip_atomic_load(consprog, __ATOMIC_RELAXED,
                                         __HIP_MEMORY_SCOPE_AGENT) < t - 47) { }
            }
            const float go = gbuf2[w][l];
            const float gf = gbuf2[w][32 + l];
            const float gi = gbuf2[w][64 + l];
            const float gg = gbuf2[w][96 + l];
            const float so = 1.f / (1.f + __expf(-go));
            const float sf = 1.f / (1.f + __expf(-gf));
            const float si = 1.f / (1.f + __expf(-gi));
            const float tg = 2.f / (1.f + __expf(-2.f * gg)) - 1.f;
            const float nc = sf * pc + si * tg;
            const float th = 2.f / (1.f + __expf(-2.f * nc)) - 1.f;
            const float nh = so * th;
            pc = nc;
            phs[par ^ 1][w + 1][j] = nh;

            const int ph4 = t & 3;
            if (ph4 == 0) ob0 = nh;
            else if (ph4 == 1) ob1 = nh;
            else if (ph4 == 2) ob2 = nh;
            else *(float4*)(outrow + (t - 3)) = make_float4(ob0, ob1, ob2, nh);

            if (w == 7 && k < 15) {
                unsigned long long q = ((unsigned long long)(unsigned)(t + 1) << 32)
                                     | (unsigned long long)__float_as_uint(nh);
                __hip_atomic_store(&dstbase[(size_t)(t & (DEPTH - 1)) * BO], q,
                                   __ATOMIC_RELAXED, __HIP_MEMORY_SCOPE_AGENT);
            }
            if (w == 0 && l == 0) {
                __hip_atomic_store(myprog, t + 1, __ATOMIC_RELAXED,
                                   __HIP_MEMORY_SCOPE_AGENT);
            }
        }
        __syncthreads();
    }
}

extern "C" void kernel_launch(void* const* d_in, const int* in_sizes, int n_in,
                              void* d_out, int out_size, void* d_ws, size_t ws_size,
                              hipStream_t stream) {
    const float* x  = (const float*)d_in[0];
    const float* W2 = (const float*)d_in[1];
    const float* b2 = (const float*)d_in[2];
    const float* W1 = (const float*)d_in[3];
    const float* b1 = (const float*)d_in[4];
    float* out = (float*)d_out;

    int* progress = (int*)d_ws;
    unsigned long long* hand = (unsigned long long*)((char*)d_ws + 4096);
    _Float16* i2sh = (_Float16*)((char*)d_ws + 4096 + RINGSZ);

    const size_t need = 4096 + RINGSZ + I2SHSZ;

    // clear progress + ring tags (stale tags alias across graph replays)
    hipMemsetAsync(d_ws, 0, 4096 + RINGSZ, stream);

    if (ws_size >= need) {
        hipLaunchKernelGGL(i2s_gemm_h, dim3(BATCH * HH), dim3(256), 0, stream,
                           x, W2, b2, b1, i2sh);
        hipLaunchKernelGGL(diag_lstm_scan_v16, dim3(BATCH * NCH), dim3(512), 0, stream,
                           W1, out, progress, hand, i2sh);
    } else {
        hipLaunchKernelGGL(diag_lstm_scan_v4, dim3(BATCH * 16), dim3(512), 0, stream,
                           x, W2, b2, W1, b1, out, progress, hand);
    }
}

// Round 17
// 259.074 us; speedup vs baseline: 1.9818x; 1.0298x over previous
//
#include <hip/hip_runtime.h>
#include <stdint.h>

#define BATCH 16
#define CIN   32
#define HH    128
#define WW    128
#define BO    32
#define OCH   128   // 4*BO
#define NCH   8     // chunks of 16 rows
#define RPC   16
#define DEPTH 64

#define PHP   40    // padded phs row (v10-proven: zero bank conflicts)

// ws: [0,4096) progress; [4096,+RINGMAX) ring (sized for fallback's 16 chunks)
//     [4096+RINGMAX, +I2SHSZ) i2s f16 [b][t][row][o]
#define RINGMAX ((size_t)BATCH * 16 * DEPTH * BO * 8)
#define I2SHSZ  ((size_t)BATCH * WW * HH * OCH * 2)

typedef _Float16 f16x8 __attribute__((ext_vector_type(8)));
typedef float    f32x4 __attribute__((ext_vector_type(4)));

// ===== K1: i2s_h[b][t][row][o] = (f16)(b2+b1 + sum_c W2[o][c]*xskew) ========
__global__ __launch_bounds__(256, 4) void i2s_gemm_h(
    const float* __restrict__ x, const float* __restrict__ W2g,
    const float* __restrict__ b2, const float* __restrict__ b1,
    _Float16* __restrict__ i2sh)
{
    const int tid = threadIdx.x;
    const int bx  = blockIdx.x;
    const int b   = bx >> 7;
    const int row = bx & 127;

    __shared__ __attribute__((aligned(16))) float xs[CIN][WW];
    __shared__ __attribute__((aligned(16))) float w2s[CIN][OCH];
    __shared__ float bs[OCH];

    for (int i = tid; i < CIN * OCH; i += 256) {
        const int c = i >> 7, o = i & 127;
        w2s[c][o] = W2g[o * CIN + c];
    }
    if (tid < OCH) bs[tid] = b2[tid] + b1[tid];
    for (int i = tid; i < CIN * WW; i += 256) {
        const int c = i >> 7, t = i & 127;
        xs[c][t] = (t >= row)
            ? x[((size_t)(b * CIN + c) * HH + row) * WW + (t - row)] : 0.f;
    }
    __syncthreads();

    const int tm = tid >> 4;
    const int tn = tid & 15;
    const int t0 = tm * 8, o0 = tn * 8;

    float bv[8];
    *(float4*)&bv[0] = *(const float4*)&bs[o0];
    *(float4*)&bv[4] = *(const float4*)&bs[o0 + 4];
    float acc[8][8];
#pragma unroll
    for (int i = 0; i < 8; ++i)
#pragma unroll
        for (int jj = 0; jj < 8; ++jj) acc[i][jj] = bv[jj];

    for (int c = 0; c < CIN; ++c) {
        float a[8], wv[8];
        *(float4*)&a[0]  = *(const float4*)&xs[c][t0];
        *(float4*)&a[4]  = *(const float4*)&xs[c][t0 + 4];
        *(float4*)&wv[0] = *(const float4*)&w2s[c][o0];
        *(float4*)&wv[4] = *(const float4*)&w2s[c][o0 + 4];
#pragma unroll
        for (int i = 0; i < 8; ++i)
#pragma unroll
            for (int jj = 0; jj < 8; ++jj)
                acc[i][jj] = fmaf(a[i], wv[jj], acc[i][jj]);
    }

#pragma unroll
    for (int i = 0; i < 8; ++i) {
        f16x8 hv;
#pragma unroll
        for (int jj = 0; jj < 8; ++jj) hv[jj] = (_Float16)acc[i][jj];
        *(f16x8*)&i2sh[((size_t)(b * WW + (t0 + i)) * HH + row) * OCH + o0] = hv;
    }
}

// ===== K2 v17: 2-wave blocks, register-local cells, LDS weights, 1 barrier.
// 128 blocks (16 img x 8 chunks of 16 rows) x 128 threads. Wave p owns
// N-tiles {p,p+2,p+4,p+6}: lane's acc[s][e] holds ALL 4 gates of its cells
// (v12 D-frag geometry) -> no gbuf round trip, 2-wave barrier skew. W1 lives
// in LDS (v14 trick: per-step ds_read_b128 B-frags, allocator cannot sink).
// phs f32/PHP=40 + v10 A-build (proven zero-conflict). Ring = v10 @ NCH=8.
__global__ __launch_bounds__(128) void diag_lstm_scan_v17(
    const float* __restrict__ W1g, float* __restrict__ out,
    int* __restrict__ progress, unsigned long long* __restrict__ hand,
    const _Float16* __restrict__ i2sh)
{
    const int tid = threadIdx.x;
    const int l   = tid & 63;
    const int p   = tid >> 6;        // wave 0..1 (N-parity)
    const int kq  = l >> 4;          // 0..3
    const int col = l & 15;
    const int blk = blockIdx.x;
    const int b   = blk & 15;        // chain (b, k=0..7) strides 16 -> same XCD
    const int k   = blk >> 4;        // 0..7

    __shared__ _Float16 W1s[OCH][72];          // [o][kk=32h+2c+z], pad 72
    __shared__ __attribute__((aligned(16))) float phs[2][RPC + 1][PHP];

    for (int i = tid; i < OCH * CIN; i += 128) {
        const int o = i >> 5, c = i & 31;
        const float2 wv = *(const float2*)&W1g[((size_t)o * CIN + c) * 2];
        W1s[o][2 * c]     = (_Float16)wv.x;    // z=0: W1_prev
        W1s[o][2 * c + 1] = (_Float16)wv.y;    // z=1: W1_cur
    }
    for (int i = tid; i < 2 * (RPC + 1) * PHP; i += 128) ((float*)phs)[i] = 0.f;

    // ---- cell/gate geometry: 4 cells/lane at local rows 4kq..4kq+3, ch j ----
    const int j     = 16 * p + col;
    const int rl0   = 4 * kq;
    const int grow0 = k * RPC + rl0;
    float pc[4] = {0.f, 0.f, 0.f, 0.f};

    // ---- i2s per-lane prefetch (1-deep): u[s][e] = i2s[t][grow0+e][j+32s] ----
    const ushort* i2su = (const ushort*)i2sh;
    ushort u[4][4];
    {
        const size_t base = ((size_t)(b * WW + 0) * HH + grow0) * OCH + j;
#pragma unroll
        for (int s = 0; s < 4; ++s)
#pragma unroll
            for (int e = 0; e < 4; ++e)
                u[s][e] = i2su[base + (size_t)e * OCH + 32 * s];
    }

    // ---- ring handoff (v10 convention) ----
    const int kprev = (k > 0) ? k - 1 : 0;
    const unsigned long long* srcbase =
        hand + (size_t)((b * NCH + kprev) * DEPTH) * BO + (l & 31);
    unsigned long long* dstbase =
        hand + (size_t)((b * NCH + k) * DEPTH) * BO + j;
    int* myprog   = progress + (b * NCH + k);
    int* consprog = myprog + 1;
    unsigned long long pre = 0ull;

    __syncthreads();

    for (int t = 0; t < WW; ++t) {
        const int par = t & 1;

        // ---- boundary poll: both waves redundantly (idempotent) ----
        if (k > 0 && t > 0) {
            unsigned long long q = pre;
            while (__any((unsigned)(q >> 32) != (unsigned)t)) {
                q = __hip_atomic_load(&srcbase[(size_t)((t - 1) & (DEPTH - 1)) * BO],
                                      __ATOMIC_RELAXED, __HIP_MEMORY_SCOPE_AGENT);
            }
            if (l < 32) phs[par][0][l] = __uint_as_float((unsigned)q);
            pre = __hip_atomic_load(&srcbase[(size_t)(t & (DEPTH - 1)) * BO],
                                    __ATOMIC_RELAXED, __HIP_MEMORY_SCOPE_AGENT);
            asm volatile("s_waitcnt lgkmcnt(0)" ::: "memory");
        }

        // ---- A-frags (v10 pattern, rows col/col+1; M=16 fully used) ----
        f16x8 af0, af1;
        {
            const float4 P0 = *(const float4*)&phs[par][col][4 * kq];
            const float4 Q0 = *(const float4*)&phs[par][col + 1][4 * kq];
            const float4 P1 = *(const float4*)&phs[par][col][16 + 4 * kq];
            const float4 Q1 = *(const float4*)&phs[par][col + 1][16 + 4 * kq];
            af0[0] = (_Float16)P0.x; af0[1] = (_Float16)Q0.x;
            af0[2] = (_Float16)P0.y; af0[3] = (_Float16)Q0.y;
            af0[4] = (_Float16)P0.z; af0[5] = (_Float16)Q0.z;
            af0[6] = (_Float16)P0.w; af0[7] = (_Float16)Q0.w;
            af1[0] = (_Float16)P1.x; af1[1] = (_Float16)Q1.x;
            af1[2] = (_Float16)P1.y; af1[3] = (_Float16)Q1.y;
            af1[4] = (_Float16)P1.z; af1[5] = (_Float16)Q1.z;
            af1[6] = (_Float16)P1.w; af1[7] = (_Float16)Q1.w;
        }

        // ---- 4 N-tile groups x 2 MFMAs; B-frags from LDS each step ----
        f32x4 acc[4];
#pragma unroll
        for (int s = 0; s < 4; ++s) {
            const int o = (p + 2 * s) * 16 + col;
#pragma unroll
            for (int e = 0; e < 4; ++e) {
                ushort uv = u[s][e];
                acc[s][e] = (float)(*reinterpret_cast<const _Float16*>(&uv));
            }
            const f16x8 bw0 = *(const f16x8*)&W1s[o][8 * kq];
            const f16x8 bw1 = *(const f16x8*)&W1s[o][32 + 8 * kq];
            acc[s] = __builtin_amdgcn_mfma_f32_16x16x32_f16(af0, bw0, acc[s], 0, 0, 0);
            acc[s] = __builtin_amdgcn_mfma_f32_16x16x32_f16(af1, bw1, acc[s], 0, 0, 0);
        }

        // ---- refill i2s prefetch for t+1 ----
        {
            const int tn = (t + 1 < WW) ? t + 1 : WW - 1;
            const size_t base = ((size_t)(b * WW + tn) * HH + grow0) * OCH + j;
#pragma unroll
            for (int s = 0; s < 4; ++s)
#pragma unroll
                for (int e = 0; e < 4; ++e)
                    u[s][e] = i2su[base + (size_t)e * OCH + 32 * s];
        }

        // ---- back-pressure: keep ring lead < DEPTH ----
        if (p == 1 && k < NCH - 1 && l == 0 && (t & 15) == 0 && t >= 48) {
            while (__hip_atomic_load(consprog, __ATOMIC_RELAXED,
                                     __HIP_MEMORY_SCOPE_AGENT) < t - 39) { }
        }

        // ---- cells: 4/lane, fully register-local ----
#pragma unroll
        for (int e = 0; e < 4; ++e) {
            const float go = acc[0][e], gf = acc[1][e], gi = acc[2][e], gg = acc[3][e];
            const float so = 1.f / (1.f + __expf(-go));
            const float sf = 1.f / (1.f + __expf(-gf));
            const float si = 1.f / (1.f + __expf(-gi));
            const float tg = 2.f / (1.f + __expf(-2.f * gg)) - 1.f;
            const float nc = sf * pc[e] + si * tg;
            const float th = 2.f / (1.f + __expf(-2.f * nc)) - 1.f;
            const float nh = so * th;
            pc[e] = nc;
            phs[par ^ 1][rl0 + e + 1][j] = nh;
            out[((size_t)(b * BO + j) * HH + (grow0 + e)) * WW + t] = nh;
            if (kq == 3 && e == 3 && k < NCH - 1) {   // local row 15: handoff
                unsigned long long qq =
                    ((unsigned long long)(unsigned)(t + 1) << 32)
                  | (unsigned long long)__float_as_uint(nh);
                __hip_atomic_store(&dstbase[(size_t)(t & 63) * BO], qq,
                                   __ATOMIC_RELAXED, __HIP_MEMORY_SCOPE_AGENT);
            }
        }
        if (tid == 0) {
            __hip_atomic_store(myprog, t + 1, __ATOMIC_RELAXED,
                               __HIP_MEMORY_SCOPE_AGENT);
        }

        __syncthreads();   // single barrier: phs[par^1] published
    }
}

// ===================== fallback (R4, proven, ws-lean) =====================
__global__ __launch_bounds__(512, 2) void diag_lstm_scan_v4(
    const float* __restrict__ x, const float* __restrict__ W2g,
    const float* __restrict__ b2, const float* __restrict__ W1g,
    const float* __restrict__ b1, float* __restrict__ out,
    int* __restrict__ progress, unsigned long long* __restrict__ hand)
{
    const int tid = threadIdx.x;
    const int l   = tid & 63;
    const int w   = tid >> 6;
    const int blk = blockIdx.x;
    const int b = (blk & 7) + ((blk >> 7) << 3);
    const int k = (blk >> 3) & 15;
    const int row = k * 8 + w;

    __shared__ __attribute__((aligned(16))) float phs[2][9][BO];
    __shared__ __attribute__((aligned(16))) float xbuf[8][CIN];
    __shared__ __attribute__((aligned(16))) float gbuf2[8][OCH];

    for (int i = tid; i < 2 * 9 * BO; i += 512) ((float*)phs)[i] = 0.f;

    const int o0 = 2 * l, o1 = 2 * l + 1;
    float w2a[CIN], w2b[CIN], w1pa[CIN], w1ca[CIN], w1pb[CIN], w1cb[CIN];
#pragma unroll
    for (int c = 0; c < CIN; ++c) {
        w2a[c]  = W2g[o0 * CIN + c];
        w2b[c]  = W2g[o1 * CIN + c];
        w1pa[c] = W1g[(o0 * CIN + c) * 2 + 0];
        w1ca[c] = W1g[(o0 * CIN + c) * 2 + 1];
        w1pb[c] = W1g[(o1 * CIN + c) * 2 + 0];
        w1cb[c] = W1g[(o1 * CIN + c) * 2 + 1];
    }
    const float biasA = b2[o0] + b1[o0];
    const float biasB = b2[o1] + b1[o1];

    const int j = l & 31;
    float pc = 0.f, ob0 = 0.f, ob1 = 0.f, ob2 = 0.f;
    float* outrow = out + ((size_t)(b * BO + j) * HH + row) * WW;

    const int kprev = (k > 0) ? k - 1 : 0;
    const unsigned long long* srcbase =
        hand + (size_t)((b * 16 + kprev) * DEPTH) * BO + j;
    unsigned long long* dstbase =
        hand + (size_t)((b * 16 + k) * DEPTH) * BO + j;
    int* myprog   = progress + (b * 16 + k);
    int* consprog = myprog + 1;

    unsigned long long pre = 0ull;
    __syncthreads();

    for (int t = 0; t < WW; ++t) {
        const int par = t & 1;
        if (l < 32) {
            const int wp = t - row;
            xbuf[w][l] = (wp >= 0)
                ? x[((size_t)(b * CIN + l) * HH + row) * WW + wp] : 0.f;
        }
        if (w == 0 && k > 0) {
            if (t > 0) {
                unsigned long long q = pre;
                while (__any((unsigned)(q >> 32) != (unsigned)t)) {
                    q = __hip_atomic_load(&srcbase[(size_t)((t - 1) & (DEPTH - 1)) * BO],
                                          __ATOMIC_RELAXED, __HIP_MEMORY_SCOPE_AGENT);
                }
                if (l < 32) phs[par][0][l] = __uint_as_float((unsigned)q);
            }
            pre = __hip_atomic_load(&srcbase[(size_t)(t & (DEPTH - 1)) * BO],
                                    __ATOMIC_RELAXED, __HIP_MEMORY_SCOPE_AGENT);
        }
        asm volatile("s_waitcnt lgkmcnt(0)" ::: "memory");

        float ga = biasA, gb = biasB;
        {
            const float4* xb4 = (const float4*)(&xbuf[w][0]);
            const float4* pv4 = (const float4*)(&phs[par][w][0]);
            const float4* qv4 = (const float4*)(&phs[par][w + 1][0]);
#pragma unroll
            for (int cc = 0; cc < CIN / 4; ++cc) {
                const float4 xv = xb4[cc];
                const float4 pv = pv4[cc];
                const float4 qv = qv4[cc];
                const float* xs = (const float*)&xv;
                const float* ps = (const float*)&pv;
                const float* qs = (const float*)&qv;
#pragma unroll
                for (int ci = 0; ci < 4; ++ci) {
                    const int c = 4 * cc + ci;
                    ga = fmaf(w2a[c],  xs[ci], ga);
                    gb = fmaf(w2b[c],  xs[ci], gb);
                    ga = fmaf(w1pa[c], ps[ci], ga);
                    gb = fmaf(w1pb[c], ps[ci], gb);
                    ga = fmaf(w1ca[c], qs[ci], ga);
                    gb = fmaf(w1cb[c], qs[ci], gb);
                }
            }
        }
        *(float2*)&gbuf2[w][o0] = make_float2(ga, gb);
        asm volatile("s_waitcnt lgkmcnt(0)" ::: "memory");

        if (l < 32) {
            if (w == 7 && k < 15 && (t & 15) == 0 && t >= 48) {
                while (__hip_atomic_load(consprog, __ATOMIC_RELAXED,
                                         __HIP_MEMORY_SCOPE_AGENT) < t - 47) { }
            }
            const float go = gbuf2[w][l];
            const float gf = gbuf2[w][32 + l];
            const float gi = gbuf2[w][64 + l];
            const float gg = gbuf2[w][96 + l];
            const float so = 1.f / (1.f + __expf(-go));
            const float sf = 1.f / (1.f + __expf(-gf));
            const float si = 1.f / (1.f + __expf(-gi));
            const float tg = 2.f / (1.f + __expf(-2.f * gg)) - 1.f;
            const float nc = sf * pc + si * tg;
            const float th = 2.f / (1.f + __expf(-2.f * nc)) - 1.f;
            const float nh = so * th;
            pc = nc;
            phs[par ^ 1][w + 1][j] = nh;

            const int ph4 = t & 3;
            if (ph4 == 0) ob0 = nh;
            else if (ph4 == 1) ob1 = nh;
            else if (ph4 == 2) ob2 = nh;
            else *(float4*)(outrow + (t - 3)) = make_float4(ob0, ob1, ob2, nh);

            if (w == 7 && k < 15) {
                unsigned long long q = ((unsigned long long)(unsigned)(t + 1) << 32)
                                     | (unsigned long long)__float_as_uint(nh);
                __hip_atomic_store(&dstbase[(size_t)(t & (DEPTH - 1)) * BO], q,
                                   __ATOMIC_RELAXED, __HIP_MEMORY_SCOPE_AGENT);
            }
            if (w == 0 && l == 0) {
                __hip_atomic_store(myprog, t + 1, __ATOMIC_RELAXED,
                                   __HIP_MEMORY_SCOPE_AGENT);
            }
        }
        __syncthreads();
    }
}

extern "C" void kernel_launch(void* const* d_in, const int* in_sizes, int n_in,
                              void* d_out, int out_size, void* d_ws, size_t ws_size,
                              hipStream_t stream) {
    const float* x  = (const float*)d_in[0];
    const float* W2 = (const float*)d_in[1];
    const float* b2 = (const float*)d_in[2];
    const float* W1 = (const float*)d_in[3];
    const float* b1 = (const float*)d_in[4];
    float* out = (float*)d_out;

    int* progress = (int*)d_ws;
    unsigned long long* hand = (unsigned long long*)((char*)d_ws + 4096);
    _Float16* i2sh = (_Float16*)((char*)d_ws + 4096 + RINGMAX);

    const size_t need = 4096 + RINGMAX + I2SHSZ;

    // clear progress + ring tags (stale tags alias across graph replays)
    hipMemsetAsync(d_ws, 0, 4096 + RINGMAX, stream);

    if (ws_size >= need) {
        hipLaunchKernelGGL(i2s_gemm_h, dim3(BATCH * HH), dim3(256), 0, stream,
                           x, W2, b2, b1, i2sh);
        hipLaunchKernelGGL(diag_lstm_scan_v17, dim3(BATCH * NCH), dim3(128), 0,
                           stream, W1, out, progress, hand, i2sh);
    } else {
        hipLaunchKernelGGL(diag_lstm_scan_v4, dim3(BATCH * 16), dim3(512), 0,
                           stream, x, W2, b2, W1, b1, out, progress, hand);
    }
}

// Round 18
// 210.263 us; speedup vs baseline: 2.4419x; 1.2321x over previous
//
#include <hip/hip_runtime.h>
#include <stdint.h>

#define BATCH 16
#define CIN   32
#define HH    128
#define WW    128
#define BO    32
#define OCH   128   // 4*BO
#define NCH   16    // h-chunks (8 rows each)
#define DEPTH 64    // handoff ring depth

#define PHP   40    // padded phs row (v10-proven, zero conflicts)
#define GBP   132   // padded gbuf row

// ws: [0,4096) progress ints
//     [4096, +RINGSZ) tagged handoff ring
//     [4096+RINGSZ, +I2SHSZ) i2s buffer (f16, layout [b][t][row][o])
#define RINGSZ ((size_t)BATCH * NCH * DEPTH * BO * 8)
#define I2SHSZ ((size_t)BATCH * WW * HH * OCH * 2)

typedef _Float16 f16x8 __attribute__((ext_vector_type(8)));
typedef float    f32x4 __attribute__((ext_vector_type(4)));

// ===== K1: i2s_h[b][t][row][o] = (f16)(b2+b1 + sum_c W2[o][c]*xskew) ========
__global__ __launch_bounds__(256, 4) void i2s_gemm_h(
    const float* __restrict__ x, const float* __restrict__ W2g,
    const float* __restrict__ b2, const float* __restrict__ b1,
    _Float16* __restrict__ i2sh)
{
    const int tid = threadIdx.x;
    const int bx  = blockIdx.x;
    const int b   = bx >> 7;
    const int row = bx & 127;

    __shared__ __attribute__((aligned(16))) float xs[CIN][WW];
    __shared__ __attribute__((aligned(16))) float w2s[CIN][OCH];
    __shared__ float bs[OCH];

    for (int i = tid; i < CIN * OCH; i += 256) {
        const int c = i >> 7, o = i & 127;
        w2s[c][o] = W2g[o * CIN + c];
    }
    if (tid < OCH) bs[tid] = b2[tid] + b1[tid];
    for (int i = tid; i < CIN * WW; i += 256) {
        const int c = i >> 7, t = i & 127;
        xs[c][t] = (t >= row)
            ? x[((size_t)(b * CIN + c) * HH + row) * WW + (t - row)] : 0.f;
    }
    __syncthreads();

    const int tm = tid >> 4;
    const int tn = tid & 15;
    const int t0 = tm * 8, o0 = tn * 8;

    float bv[8];
    *(float4*)&bv[0] = *(const float4*)&bs[o0];
    *(float4*)&bv[4] = *(const float4*)&bs[o0 + 4];
    float acc[8][8];
#pragma unroll
    for (int i = 0; i < 8; ++i)
#pragma unroll
        for (int jj = 0; jj < 8; ++jj) acc[i][jj] = bv[jj];

    for (int c = 0; c < CIN; ++c) {
        float a[8], wv[8];
        *(float4*)&a[0]  = *(const float4*)&xs[c][t0];
        *(float4*)&a[4]  = *(const float4*)&xs[c][t0 + 4];
        *(float4*)&wv[0] = *(const float4*)&w2s[c][o0];
        *(float4*)&wv[4] = *(const float4*)&w2s[c][o0 + 4];
#pragma unroll
        for (int i = 0; i < 8; ++i)
#pragma unroll
            for (int jj = 0; jj < 8; ++jj)
                acc[i][jj] = fmaf(a[i], wv[jj], acc[i][jj]);
    }

#pragma unroll
    for (int i = 0; i < 8; ++i) {
        f16x8 hv;
#pragma unroll
        for (int jj = 0; jj < 8; ++jj) hv[jj] = (_Float16)acc[i][jj];
        *(f16x8*)&i2sh[((size_t)(b * WW + (t0 + i)) * HH + row) * OCH + o0] = hv;
    }
}

// ===== K2 v18: v10 verbatim; the two s_barriers replaced by ONE-COUNTER
// LDS mailbox (1 ds_atomic_add by lane0/wave + 1 broadcast ds_read spin).
// R16's mailbox failed because its spin was 8 reads + 7-op min-tree per iter;
// this one is 1 read + 1 cmp. No s_barrier -> no vmcnt(0) drain: prefetch
// loads and out stores stay in flight across sync points.
__global__ __launch_bounds__(512) void diag_lstm_scan_v18(
    const float* __restrict__ W1g, float* __restrict__ out,
    int* __restrict__ progress, unsigned long long* __restrict__ hand,
    const _Float16* __restrict__ i2sh)
{
    const int tid = threadIdx.x;
    const int l   = tid & 63;
    const int wv  = tid >> 6;          // wave 0..7
    const int blk = blockIdx.x;
    const int b = (blk & 7) + ((blk >> 7) << 3);   // XCD-affinity remap
    const int k = (blk >> 3) & (NCH - 1);

    __shared__ __attribute__((aligned(16))) float    phs[2][9][PHP];
    __shared__ __attribute__((aligned(16))) float    gbuf[8][GBP];
    __shared__ __attribute__((aligned(16))) _Float16 ibuf[2][8][OCH];
    __shared__ int cnt;

    for (int i = tid; i < 2 * 9 * PHP; i += 512) ((float*)phs)[i] = 0.f;
    if (tid == 0) cnt = 0;

    // ---- B-frags: W[o][kk] = W1g[o*64 + kk], loaded once (8 VGPRs ok) ----
    const int n  = l & 15;
    const int kq = l >> 4;
    const int o  = wv * 16 + n;
    f16x8 bw0, bw1;
    {
        const float4 a0 = *(const float4*)&W1g[(size_t)o * 64 + 8 * kq];
        const float4 a1 = *(const float4*)&W1g[(size_t)o * 64 + 8 * kq + 4];
        const float4 c0 = *(const float4*)&W1g[(size_t)o * 64 + 32 + 8 * kq];
        const float4 c1 = *(const float4*)&W1g[(size_t)o * 64 + 32 + 8 * kq + 4];
        bw0[0] = (_Float16)a0.x; bw0[1] = (_Float16)a0.y;
        bw0[2] = (_Float16)a0.z; bw0[3] = (_Float16)a0.w;
        bw0[4] = (_Float16)a1.x; bw0[5] = (_Float16)a1.y;
        bw0[6] = (_Float16)a1.z; bw0[7] = (_Float16)a1.w;
        bw1[0] = (_Float16)c0.x; bw1[1] = (_Float16)c0.y;
        bw1[2] = (_Float16)c0.z; bw1[3] = (_Float16)c0.w;
        bw1[4] = (_Float16)c1.x; bw1[5] = (_Float16)c1.y;
        bw1[6] = (_Float16)c1.z; bw1[7] = (_Float16)c1.w;
    }

    // ---- cell role (waves 0..3): row r = 2wv + (l>>5), channel j = l&31 ----
    const int r = (2 * wv + (l >> 5)) & 7;
    const int j = l & 31;
    float pc = 0.f, ob0 = 0.f, ob1 = 0.f, ob2 = 0.f;
    float* outrow = out + ((size_t)(b * BO + j) * HH + (k * 8 + r)) * WW;

    // ---- ring handoff ----
    const int kprev = (k > 0) ? k - 1 : 0;
    const unsigned long long* srcbase =
        hand + (size_t)((b * NCH + kprev) * DEPTH) * BO + j;
    unsigned long long* dstbase =
        hand + (size_t)((b * NCH + k) * DEPTH) * BO + j;
    int* myprog   = progress + (b * NCH + k);
    int* consprog = myprog + 1;
    unsigned long long pre = 0ull;

    // ---- i2s prefetch: [b][t][row][o] f16; block slice = 8 rows = 2KB/t ----
    const size_t islab = (size_t)HH * OCH;
    const _Float16* ibase0 = i2sh + ((size_t)(b * WW) * HH + k * 8) * OCH;
    const int ii = tid & 255;
    uint2 pr0 = make_uint2(0, 0), pr1 = make_uint2(0, 0);

    ((unsigned int*)&ibuf[0][0][0])[tid] = ((const unsigned int*)ibase0)[tid]; // t=0
    if (wv >= 4) {
        pr0 = ((const uint2*)(ibase0 + 1 * islab))[ii];   // t=1
        pr1 = ((const uint2*)(ibase0 + 2 * islab))[ii];   // t=2
    }
    __syncthreads();

    for (int t = 0; t < WW; ++t) {
        const int par = t & 1;

        // ---- boundary poll (all waves, idempotent writes) ----
        if (k > 0 && t > 0) {
            unsigned long long q = pre;
            while (__any((unsigned)(q >> 32) != (unsigned)t)) {
                q = __hip_atomic_load(&srcbase[(size_t)((t - 1) & (DEPTH - 1)) * BO],
                                      __ATOMIC_RELAXED, __HIP_MEMORY_SCOPE_AGENT);
            }
            if (l < 32) phs[par][0][l] = __uint_as_float((unsigned)q);
            pre = __hip_atomic_load(&srcbase[(size_t)(t & (DEPTH - 1)) * BO],
                                    __ATOMIC_RELAXED, __HIP_MEMORY_SCOPE_AGENT);
            asm volatile("s_waitcnt lgkmcnt(0)" ::: "memory");
        }

        // ---- A-frags from phs (m = n = l&15; rows >= 8 are zero padding) ----
        f16x8 af0 = {}; f16x8 af1 = {};
        if (n < 8) {
            const float4 P0 = *(const float4*)&phs[par][n    ][4 * kq];
            const float4 Q0 = *(const float4*)&phs[par][n + 1][4 * kq];
            const float4 P1 = *(const float4*)&phs[par][n    ][16 + 4 * kq];
            const float4 Q1 = *(const float4*)&phs[par][n + 1][16 + 4 * kq];
            af0[0] = (_Float16)P0.x; af0[1] = (_Float16)Q0.x;
            af0[2] = (_Float16)P0.y; af0[3] = (_Float16)Q0.y;
            af0[4] = (_Float16)P0.z; af0[5] = (_Float16)Q0.z;
            af0[6] = (_Float16)P0.w; af0[7] = (_Float16)Q0.w;
            af1[0] = (_Float16)P1.x; af1[1] = (_Float16)Q1.x;
            af1[2] = (_Float16)P1.y; af1[3] = (_Float16)Q1.y;
            af1[4] = (_Float16)P1.z; af1[5] = (_Float16)Q1.z;
            af1[6] = (_Float16)P1.w; af1[7] = (_Float16)Q1.w;
        }

        f32x4 acc = {0.f, 0.f, 0.f, 0.f};
        acc = __builtin_amdgcn_mfma_f32_16x16x32_f16(af0, bw0, acc, 0, 0, 0);
        acc = __builtin_amdgcn_mfma_f32_16x16x32_f16(af1, bw1, acc, 0, 0, 0);

        // ---- gate write: lane l<32 holds rows 4*kq+e, col n ----
        if (l < 32) {
#pragma unroll
            for (int e = 0; e < 4; ++e)
                gbuf[4 * kq + e][wv * 16 + n] = acc[e];
        }

        // ---- waves 4..7: stage i2s for t+1, issue load for t+3 ----
        if (wv >= 4) {
            ((uint2*)&ibuf[(t + 1) & 1][0][0])[ii] = pr0;   // waits pr0's own vmcnt
            pr0 = pr1;
            const int t3 = (t + 3 < WW) ? t + 3 : WW - 1;
            pr1 = ((const uint2*)(ibase0 + (size_t)t3 * islab))[ii];
        }

        // ==== sync A: 1-counter mailbox (no vmcnt drain) ====
        {
            asm volatile("s_waitcnt lgkmcnt(0)" ::: "memory");
            if (l == 0)
                __hip_atomic_fetch_add(&cnt, 1, __ATOMIC_RELAXED,
                                       __HIP_MEMORY_SCOPE_WORKGROUP);
            const int tgt = 8 * (2 * t + 1);
            while (__hip_atomic_load(&cnt, __ATOMIC_RELAXED,
                                     __HIP_MEMORY_SCOPE_WORKGROUP) < tgt) {}
        }

        // ---- cell update (waves 0..3) ----
        if (wv < 4) {
            if (wv == 3 && l >= 32 && k < NCH - 1 && (t & 15) == 0 && t >= 48) {
                while (__hip_atomic_load(consprog, __ATOMIC_RELAXED,
                                         __HIP_MEMORY_SCOPE_AGENT) < t - 47) { }
            }
            const float go = gbuf[r][j]      + (float)ibuf[par][r][j];
            const float gf = gbuf[r][32 + j] + (float)ibuf[par][r][32 + j];
            const float gi = gbuf[r][64 + j] + (float)ibuf[par][r][64 + j];
            const float gg = gbuf[r][96 + j] + (float)ibuf[par][r][96 + j];
            const float so = 1.f / (1.f + __expf(-go));
            const float sf = 1.f / (1.f + __expf(-gf));
            const float si = 1.f / (1.f + __expf(-gi));
            const float tg = 2.f / (1.f + __expf(-2.f * gg)) - 1.f;
            const float nc = sf * pc + si * tg;
            const float th = 2.f / (1.f + __expf(-2.f * nc)) - 1.f;
            const float nh = so * th;
            pc = nc;
            phs[par ^ 1][r + 1][j] = nh;

            const int ph4 = t & 3;
            if (ph4 == 0) ob0 = nh;
            else if (ph4 == 1) ob1 = nh;
            else if (ph4 == 2) ob2 = nh;
            else *(float4*)(outrow + (t - 3)) = make_float4(ob0, ob1, ob2, nh);

            if (wv == 3 && l >= 32 && k < NCH - 1) {   // r==7: handoff
                unsigned long long qq = ((unsigned long long)(unsigned)(t + 1) << 32)
                                      | (unsigned long long)__float_as_uint(nh);
                __hip_atomic_store(&dstbase[(size_t)(t & (DEPTH - 1)) * BO], qq,
                                   __ATOMIC_RELAXED, __HIP_MEMORY_SCOPE_AGENT);
            }
            if (tid == 0) {
                __hip_atomic_store(myprog, t + 1, __ATOMIC_RELAXED,
                                   __HIP_MEMORY_SCOPE_AGENT);
            }
        }

        // ==== sync B ====
        {
            asm volatile("s_waitcnt lgkmcnt(0)" ::: "memory");
            if (l == 0)
                __hip_atomic_fetch_add(&cnt, 1, __ATOMIC_RELAXED,
                                       __HIP_MEMORY_SCOPE_WORKGROUP);
            const int tgt = 8 * (2 * t + 2);
            while (__hip_atomic_load(&cnt, __ATOMIC_RELAXED,
                                     __HIP_MEMORY_SCOPE_WORKGROUP) < tgt) {}
        }
    }
}

// ===================== fallback (R4, proven, ws-lean) =====================
__global__ __launch_bounds__(512, 2) void diag_lstm_scan_v4(
    const float* __restrict__ x, const float* __restrict__ W2g,
    const float* __restrict__ b2, const float* __restrict__ W1g,
    const float* __restrict__ b1, float* __restrict__ out,
    int* __restrict__ progress, unsigned long long* __restrict__ hand)
{
    const int tid = threadIdx.x;
    const int l   = tid & 63;
    const int w   = tid >> 6;
    const int blk = blockIdx.x;
    const int b = (blk & 7) + ((blk >> 7) << 3);
    const int k = (blk >> 3) & 15;
    const int row = k * 8 + w;

    __shared__ __attribute__((aligned(16))) float phs[2][9][BO];
    __shared__ __attribute__((aligned(16))) float xbuf[8][CIN];
    __shared__ __attribute__((aligned(16))) float gbuf2[8][OCH];

    for (int i = tid; i < 2 * 9 * BO; i += 512) ((float*)phs)[i] = 0.f;

    const int o0 = 2 * l, o1 = 2 * l + 1;
    float w2a[CIN], w2b[CIN], w1pa[CIN], w1ca[CIN], w1pb[CIN], w1cb[CIN];
#pragma unroll
    for (int c = 0; c < CIN; ++c) {
        w2a[c]  = W2g[o0 * CIN + c];
        w2b[c]  = W2g[o1 * CIN + c];
        w1pa[c] = W1g[(o0 * CIN + c) * 2 + 0];
        w1ca[c] = W1g[(o0 * CIN + c) * 2 + 1];
        w1pb[c] = W1g[(o1 * CIN + c) * 2 + 0];
        w1cb[c] = W1g[(o1 * CIN + c) * 2 + 1];
    }
    const float biasA = b2[o0] + b1[o0];
    const float biasB = b2[o1] + b1[o1];

    const int j = l & 31;
    float pc = 0.f, ob0 = 0.f, ob1 = 0.f, ob2 = 0.f;
    float* outrow = out + ((size_t)(b * BO + j) * HH + row) * WW;

    const int kprev = (k > 0) ? k - 1 : 0;
    const unsigned long long* srcbase =
        hand + (size_t)((b * 16 + kprev) * DEPTH) * BO + j;
    unsigned long long* dstbase =
        hand + (size_t)((b * 16 + k) * DEPTH) * BO + j;
    int* myprog   = progress + (b * 16 + k);
    int* consprog = myprog + 1;

    unsigned long long pre = 0ull;
    __syncthreads();

    for (int t = 0; t < WW; ++t) {
        const int par = t & 1;
        if (l < 32) {
            const int wp = t - row;
            xbuf[w][l] = (wp >= 0)
                ? x[((size_t)(b * CIN + l) * HH + row) * WW + wp] : 0.f;
        }
        if (w == 0 && k > 0) {
            if (t > 0) {
                unsigned long long q = pre;
                while (__any((unsigned)(q >> 32) != (unsigned)t)) {
                    q = __hip_atomic_load(&srcbase[(size_t)((t - 1) & (DEPTH - 1)) * BO],
                                          __ATOMIC_RELAXED, __HIP_MEMORY_SCOPE_AGENT);
                }
                if (l < 32) phs[par][0][l] = __uint_as_float((unsigned)q);
            }
            pre = __hip_atomic_load(&srcbase[(size_t)(t & (DEPTH - 1)) * BO],
                                    __ATOMIC_RELAXED, __HIP_MEMORY_SCOPE_AGENT);
        }
        asm volatile("s_waitcnt lgkmcnt(0)" ::: "memory");

        float ga = biasA, gb = biasB;
        {
            const float4* xb4 = (const float4*)(&xbuf[w][0]);
            const float4* pv4 = (const float4*)(&phs[par][w][0]);
            const float4* qv4 = (const float4*)(&phs[par][w + 1][0]);
#pragma unroll
            for (int cc = 0; cc < CIN / 4; ++cc) {
                const float4 xv = xb4[cc];
                const float4 pv = pv4[cc];
                const float4 qv = qv4[cc];
                const float* xs = (const float*)&xv;
                const float* ps = (const float*)&pv;
                const float* qs = (const float*)&qv;
#pragma unroll
                for (int ci = 0; ci < 4; ++ci) {
                    const int c = 4 * cc + ci;
                    ga = fmaf(w2a[c],  xs[ci], ga);
                    gb = fmaf(w2b[c],  xs[ci], gb);
                    ga = fmaf(w1pa[c], ps[ci], ga);
                    gb = fmaf(w1pb[c], ps[ci], gb);
                    ga = fmaf(w1ca[c], qs[ci], ga);
                    gb = fmaf(w1cb[c], qs[ci], gb);
                }
            }
        }
        *(float2*)&gbuf2[w][o0] = make_float2(ga, gb);
        asm volatile("s_waitcnt lgkmcnt(0)" ::: "memory");

        if (l < 32) {
            if (w == 7 && k < 15 && (t & 15) == 0 && t >= 48) {
                while (__hip_atomic_load(consprog, __ATOMIC_RELAXED,
                                         __HIP_MEMORY_SCOPE_AGENT) < t - 47) { }
            }
            const float go = gbuf2[w][l];
            const float gf = gbuf2[w][32 + l];
            const float gi = gbuf2[w][64 + l];
            const float gg = gbuf2[w][96 + l];
            const float so = 1.f / (1.f + __expf(-go));
            const float sf = 1.f / (1.f + __expf(-gf));
            const float si = 1.f / (1.f + __expf(-gi));
            const float tg = 2.f / (1.f + __expf(-2.f * gg)) - 1.f;
            const float nc = sf * pc + si * tg;
            const float th = 2.f / (1.f + __expf(-2.f * nc)) - 1.f;
            const float nh = so * th;
            pc = nc;
            phs[par ^ 1][w + 1][j] = nh;

            const int ph4 = t & 3;
            if (ph4 == 0) ob0 = nh;
            else if (ph4 == 1) ob1 = nh;
            else if (ph4 == 2) ob2 = nh;
            else *(float4*)(outrow + (t - 3)) = make_float4(ob0, ob1, ob2, nh);

            if (w == 7 && k < 15) {
                unsigned long long q = ((unsigned long long)(unsigned)(t + 1) << 32)
                                     | (unsigned long long)__float_as_uint(nh);
                __hip_atomic_store(&dstbase[(size_t)(t & (DEPTH - 1)) * BO], q,
                                   __ATOMIC_RELAXED, __HIP_MEMORY_SCOPE_AGENT);
            }
            if (w == 0 && l == 0) {
                __hip_atomic_store(myprog, t + 1, __ATOMIC_RELAXED,
                                   __HIP_MEMORY_SCOPE_AGENT);
            }
        }
        __syncthreads();
    }
}

extern "C" void kernel_launch(void* const* d_in, const int* in_sizes, int n_in,
                              void* d_out, int out_size, void* d_ws, size_t ws_size,
                              hipStream_t stream) {
    const float* x  = (const float*)d_in[0];
    const float* W2 = (const float*)d_in[1];
    const float* b2 = (const float*)d_in[2];
    const float* W1 = (const float*)d_in[3];
    const float* b1 = (const float*)d_in[4];
    float* out = (float*)d_out;

    int* progress = (int*)d_ws;
    unsigned long long* hand = (unsigned long long*)((char*)d_ws + 4096);
    _Float16* i2sh = (_Float16*)((char*)d_ws + 4096 + RINGSZ);

    const size_t need = 4096 + RINGSZ + I2SHSZ;

    // clear progress + ring tags (stale tags alias across graph replays)
    hipMemsetAsync(d_ws, 0, 4096 + RINGSZ, stream);

    if (ws_size >= need) {
        hipLaunchKernelGGL(i2s_gemm_h, dim3(BATCH * HH), dim3(256), 0, stream,
                           x, W2, b2, b1, i2sh);
        hipLaunchKernelGGL(diag_lstm_scan_v18, dim3(BATCH * NCH), dim3(512), 0, stream,
                           W1, out, progress, hand, i2sh);
    } else {
        hipLaunchKernelGGL(diag_lstm_scan_v4, dim3(BATCH * 16), dim3(512), 0, stream,
                           x, W2, b2, W1, b1, out, progress, hand);
    }
}